// Round 1
// baseline (2058.838 us; speedup 1.0000x reference)
//
#include <hip/hip_runtime.h>
#include <cstdint>
#include <cstddef>

#define NN 8192
#define DD 512
#define HH 256
#define KTOP 21

// ---------------------------------------------------------------------------
// fp32 SGEMM: C[M,N] = act(A[M,K] @ B + bias), B row-major [K,N] or (TRANSB)
// row-major [N,K] (i.e. C = A @ B^T). 128x128 tile, BK=16, 256 threads, 8x8.
// ---------------------------------------------------------------------------
template<bool TRANSB, int ACT>
__global__ __launch_bounds__(256)
void sgemm128(const float* __restrict__ A, const float* __restrict__ B,
              const float* __restrict__ bias, float* __restrict__ C,
              int M, int N, int K) {
    constexpr int BM = 128, BN = 128, BK = 16;
    __shared__ float As[BK][BM + 4];
    __shared__ float Bs[BK][BN + 4];

    const int tiles_n = N / BN;
    const int by = blockIdx.x / tiles_n;
    const int bx = blockIdx.x % tiles_n;
    const int row0 = by * BM, col0 = bx * BN;
    const int tid = threadIdx.x;
    const int tx = tid & 15, ty = tid >> 4;

    float acc[8][8];
#pragma unroll
    for (int m = 0; m < 8; ++m)
#pragma unroll
        for (int n = 0; n < 8; ++n) acc[m][n] = 0.f;

    for (int k0 = 0; k0 < K; k0 += BK) {
        // --- stage A tile (transposed into As[k][m]) ---
#pragma unroll
        for (int l = 0; l < 2; ++l) {
            int f = tid + l * 256;          // 0..511
            int r = f >> 2, c4 = f & 3;
            float4 v = *reinterpret_cast<const float4*>(
                A + (size_t)(row0 + r) * K + k0 + c4 * 4);
            As[c4 * 4 + 0][r] = v.x;
            As[c4 * 4 + 1][r] = v.y;
            As[c4 * 4 + 2][r] = v.z;
            As[c4 * 4 + 3][r] = v.w;
        }
        // --- stage B tile ---
        if (TRANSB) {
#pragma unroll
            for (int l = 0; l < 2; ++l) {
                int f = tid + l * 256;
                int r = f >> 2, c4 = f & 3;
                float4 v = *reinterpret_cast<const float4*>(
                    B + (size_t)(col0 + r) * K + k0 + c4 * 4);
                Bs[c4 * 4 + 0][r] = v.x;
                Bs[c4 * 4 + 1][r] = v.y;
                Bs[c4 * 4 + 2][r] = v.z;
                Bs[c4 * 4 + 3][r] = v.w;
            }
        } else {
#pragma unroll
            for (int l = 0; l < 2; ++l) {
                int f = tid + l * 256;
                int kr = f >> 5, n4 = f & 31;
                *reinterpret_cast<float4*>(&Bs[kr][n4 * 4]) =
                    *reinterpret_cast<const float4*>(
                        B + (size_t)(k0 + kr) * N + col0 + n4 * 4);
            }
        }
        __syncthreads();

#pragma unroll
        for (int kk = 0; kk < BK; ++kk) {
            float a[8], b[8];
            *(float4*)&a[0] = *(const float4*)&As[kk][ty * 8];
            *(float4*)&a[4] = *(const float4*)&As[kk][ty * 8 + 4];
            *(float4*)&b[0] = *(const float4*)&Bs[kk][tx * 8];
            *(float4*)&b[4] = *(const float4*)&Bs[kk][tx * 8 + 4];
#pragma unroll
            for (int m = 0; m < 8; ++m)
#pragma unroll
                for (int n = 0; n < 8; ++n)
                    acc[m][n] = fmaf(a[m], b[n], acc[m][n]);
        }
        __syncthreads();
    }

    // --- epilogue ---
    const int crow = row0 + ty * 8;
    const int ccol = col0 + tx * 8;
    float bv[8];
#pragma unroll
    for (int n = 0; n < 8; ++n) bv[n] = bias ? bias[ccol + n] : 0.f;
#pragma unroll
    for (int m = 0; m < 8; ++m) {
        float o[8];
#pragma unroll
        for (int n = 0; n < 8; ++n) {
            float t = acc[m][n] + bv[n];
            if (ACT == 1) t = fmaxf(t, 0.f);
            o[n] = t;
        }
        *reinterpret_cast<float4*>(C + (size_t)(crow + m) * N + ccol)     = *(float4*)&o[0];
        *reinterpret_cast<float4*>(C + (size_t)(crow + m) * N + ccol + 4) = *(float4*)&o[4];
    }
}

// ---------------------------------------------------------------------------
// Row L2-normalize: emb[row] /= max(||emb[row]||, 1e-12). 256 thr, D=512.
// ---------------------------------------------------------------------------
__global__ __launch_bounds__(256)
void rownorm_kernel(float* __restrict__ emb) {
    const int row = blockIdx.x, tid = threadIdx.x;
    float* rp = emb + (size_t)row * DD;
    float v0 = rp[tid], v1 = rp[tid + 256];
    float sum = v0 * v0 + v1 * v1;
#pragma unroll
    for (int off = 32; off > 0; off >>= 1) sum += __shfl_down(sum, off, 64);
    __shared__ float ws[4];
    __shared__ float sc_sh;
    if ((tid & 63) == 0) ws[tid >> 6] = sum;
    __syncthreads();
    if (tid == 0) {
        float n = sqrtf(ws[0] + ws[1] + ws[2] + ws[3]);
        sc_sh = 1.0f / fmaxf(n, 1e-12f);
    }
    __syncthreads();
    float sc = sc_sh;
    rp[tid] = v0 * sc;
    rp[tid + 256] = v1 * sc;
}

// ---------------------------------------------------------------------------
// Per-row top-21 of sim (8192 cols). One block (256 thr) per row.
// Each thread: register insertion-sorted top-21 over its 32 strided elems.
// Merge: 21 rounds of block argmax over per-thread heads.
// ---------------------------------------------------------------------------
__global__ __launch_bounds__(256)
void topk_kernel(const float* __restrict__ sim, int* __restrict__ oidx,
                 float* __restrict__ oval) {
    const int row = blockIdx.x;
    const int tid = threadIdx.x;
    const float* r = sim + (size_t)row * NN;

    float v[KTOP];
    int   id[KTOP];
#pragma unroll
    for (int k = 0; k < KTOP; ++k) { v[k] = -INFINITY; id[k] = -1; }

    for (int j = tid; j < NN; j += 256) {
        float x = r[j];
        if (x > v[0]) {
#pragma unroll
            for (int k = 0; k < KTOP; ++k) {
                if (k < KTOP - 1 && x > v[k + 1]) {
                    v[k] = v[k + 1]; id[k] = id[k + 1];
                } else {
                    v[k] = x; id[k] = j;
                    break;
                }
            }
        }
    }

    __shared__ float lv[256][KTOP];
    __shared__ int   li[256][KTOP];
    __shared__ float rv[256];
    __shared__ int   rt[256];
#pragma unroll
    for (int k = 0; k < KTOP; ++k) { lv[tid][k] = v[k]; li[tid][k] = id[k]; }
    int mypos = KTOP - 1;
    __syncthreads();

    for (int sel = 0; sel < KTOP; ++sel) {
        rv[tid] = (mypos >= 0) ? lv[tid][mypos] : -INFINITY;
        rt[tid] = tid;
        __syncthreads();
        for (int s = 128; s > 0; s >>= 1) {
            if (tid < s && rv[tid + s] > rv[tid]) {
                rv[tid] = rv[tid + s]; rt[tid] = rt[tid + s];
            }
            __syncthreads();
        }
        int winner = rt[0];
        if (tid == winner) {
            oval[(size_t)row * KTOP + sel] = lv[tid][mypos];
            oidx[(size_t)row * KTOP + sel] = li[tid][mypos];
            mypos--;
        }
        __syncthreads();
    }
}

// ---------------------------------------------------------------------------
// Scatter: gen_adj[i,j] += 0.5*relu(s_ij) for j in topk(i), j != i; symmetric.
// s_ij == s_ji bitwise, so atomic order doesn't affect the result.
// ---------------------------------------------------------------------------
__global__ __launch_bounds__(256)
void scatter_kernel(const int* __restrict__ tidx, const float* __restrict__ tval,
                    float* __restrict__ adj) {
    int t = blockIdx.x * 256 + threadIdx.x;
    if (t >= NN * KTOP) return;
    int i = t / KTOP;
    int j = tidx[t];
    if (j == i || j < 0) return;
    float v = tval[t];
    if (v <= 0.f) return;
    v *= 0.5f;
    atomicAdd(adj + (size_t)i * NN + j, v);
    atomicAdd(adj + (size_t)j * NN + i, v);
}

// ---------------------------------------------------------------------------
// Degree: sdeg[i] = 1/(sqrt(1 + sum_j adj[i,j]) + 1e-10). One block per row.
// ---------------------------------------------------------------------------
__global__ __launch_bounds__(256)
void degree_kernel(const float* __restrict__ adj, float* __restrict__ sdeg) {
    const int row = blockIdx.x, tid = threadIdx.x;
    const float4* rp = reinterpret_cast<const float4*>(adj + (size_t)row * NN);
    float sum = 0.f;
#pragma unroll
    for (int f = tid; f < NN / 4; f += 256) {
        float4 v = rp[f];
        sum += (v.x + v.y) + (v.z + v.w);
    }
#pragma unroll
    for (int off = 32; off > 0; off >>= 1) sum += __shfl_down(sum, off, 64);
    __shared__ float ws[4];
    if ((tid & 63) == 0) ws[tid >> 6] = sum;
    __syncthreads();
    if (tid == 0) {
        float t = ws[0] + ws[1] + ws[2] + ws[3];
        sdeg[row] = 1.0f / (sqrtf(1.0f + t) + 1e-10f);
    }
}

// ---------------------------------------------------------------------------
// SpMM: Y[i,:] = act( s_i * ( sum_j adj[i,j]*s_j*X[j,:] + s_i*X[i,:] ) )
// Dense row scan + order-preserving ballot compaction (deterministic).
// One block (256 thr) per row; thread t owns channel(s) t (+256).
// ---------------------------------------------------------------------------
template<int COLS, bool DORELU>
__global__ __launch_bounds__(256)
void spmm_kernel(const float* __restrict__ adj, const float* __restrict__ sdeg,
                 const float* __restrict__ X, float* __restrict__ Y) {
    constexpr int CPT = COLS / 256;
    const int i = blockIdx.x;
    const int tid = threadIdx.x;
    const int lane = tid & 63, wave = tid >> 6;

    float acc[CPT];
#pragma unroll
    for (int c = 0; c < CPT; ++c) acc[c] = 0.f;

    __shared__ int   s_j[256];
    __shared__ float s_w[256];
    __shared__ int   s_cnt[4];

    const float si = sdeg[i];
    const float* rowp = adj + (size_t)i * NN;

    for (int j0 = 0; j0 < NN; j0 += 256) {
        float w = rowp[j0 + tid];
        bool nz = (w != 0.f);
        unsigned long long m = __ballot(nz);
        unsigned long long ltmask = (lane == 0) ? 0ull : (~0ull >> (64 - lane));
        int pre = __popcll(m & ltmask);
        if (lane == 0) s_cnt[wave] = __popcll(m);
        __syncthreads();
        int base = 0;
#pragma unroll
        for (int q = 0; q < 4; ++q)
            if (q < wave) base += s_cnt[q];
        int total = s_cnt[0] + s_cnt[1] + s_cnt[2] + s_cnt[3];
        if (nz) {
            int p = base + pre;
            s_j[p] = j0 + tid;
            s_w[p] = w * sdeg[j0 + tid];
        }
        __syncthreads();
        for (int e = 0; e < total; ++e) {
            int j = s_j[e];
            float we = s_w[e];
#pragma unroll
            for (int c = 0; c < CPT; ++c)
                acc[c] += we * X[(size_t)j * COLS + tid + c * 256];
        }
        __syncthreads();
    }

#pragma unroll
    for (int c = 0; c < CPT; ++c) {
        float val = si * (acc[c] + si * X[(size_t)i * COLS + tid + c * 256]);
        if (DORELU) val = fmaxf(val, 0.f);
        Y[(size_t)i * COLS + tid + c * 256] = val;
    }
}

// ---------------------------------------------------------------------------
extern "C" void kernel_launch(void* const* d_in, const int* in_sizes, int n_in,
                              void* d_out, int out_size, void* d_ws, size_t ws_size,
                              hipStream_t stream) {
    const float* features = (const float*)d_in[0];
    const float* masked   = (const float*)d_in[1];
    const float* W1  = (const float*)d_in[2];
    const float* b1  = (const float*)d_in[3];
    const float* W2  = (const float*)d_in[4];
    const float* b2  = (const float*)d_in[5];
    const float* Wg1 = (const float*)d_in[6];
    const float* bg1 = (const float*)d_in[7];
    const float* Wg2 = (const float*)d_in[8];
    const float* bg2 = (const float*)d_in[9];

    float* out_h3  = (float*)d_out;                      // [NN, DD]
    float* out_adj = (float*)d_out + (size_t)NN * DD;    // [NN, NN] (also sim scratch)

    float* h    = (float*)d_ws;                          // NN*DD
    float* emb  = h + (size_t)NN * DD;                   // NN*DD
    float* tval = emb + (size_t)NN * DD;                 // NN*KTOP
    int*   tidx = (int*)(tval + (size_t)NN * KTOP);      // NN*KTOP
    float* sdeg = (float*)(tidx + (size_t)NN * KTOP);    // NN
    float* x1 = emb;                                     // reuse (emb dead after sim)
    float* h1 = emb + (size_t)NN * HH;
    float* x2 = h;                                       // reuse (h dead after emb)

    dim3 blk(256);

    // 1) h = relu(features @ W1 + b1)
    sgemm128<false, 1><<<dim3((NN / 128) * (DD / 128)), blk, 0, stream>>>(
        features, W1, b1, h, NN, DD, DD);
    // 2) emb = h @ W2 + b2
    sgemm128<false, 0><<<dim3((NN / 128) * (DD / 128)), blk, 0, stream>>>(
        h, W2, b2, emb, NN, DD, DD);
    // 3) normalize rows
    rownorm_kernel<<<dim3(NN), blk, 0, stream>>>(emb);
    // 4) sim = emb @ emb^T  -> stored in out_adj region as scratch
    sgemm128<true, 0><<<dim3((NN / 128) * (NN / 128)), blk, 0, stream>>>(
        emb, emb, nullptr, out_adj, NN, NN, DD);
    // 5) top-21 per row
    topk_kernel<<<dim3(NN), blk, 0, stream>>>(out_adj, tidx, tval);
    // 6) zero gen_adj, then scatter symmetrized relu'd topk entries
    hipMemsetAsync(out_adj, 0, (size_t)NN * NN * sizeof(float), stream);
    scatter_kernel<<<dim3((NN * KTOP + 255) / 256), blk, 0, stream>>>(tidx, tval, out_adj);
    // 7) degree scale s = 1/(sqrt(1+rowsum)+eps)
    degree_kernel<<<dim3(NN), blk, 0, stream>>>(out_adj, sdeg);
    // 8) x1 = masked @ Wg1 + bg1
    sgemm128<false, 0><<<dim3((NN / 128) * (HH / 128)), blk, 0, stream>>>(
        masked, Wg1, bg1, x1, NN, HH, DD);
    // 9) h1 = relu(Ahat @ x1)
    spmm_kernel<HH, true><<<dim3(NN), blk, 0, stream>>>(out_adj, sdeg, x1, h1);
    // 10) x2 = h1 @ Wg2 + bg2
    sgemm128<false, 0><<<dim3((NN / 128) * (DD / 128)), blk, 0, stream>>>(
        h1, Wg2, bg2, x2, NN, DD, HH);
    // 11) h3 = Ahat @ x2 -> d_out
    spmm_kernel<DD, false><<<dim3(NN), blk, 0, stream>>>(out_adj, sdeg, x2, out_h3);
}

// Round 2
// 1528.616 us; speedup vs baseline: 1.3469x; 1.3469x over previous
//
#include <hip/hip_runtime.h>
#include <cstdint>
#include <cstddef>

#define NN 8192
#define DD 512
#define HH 256
#define KTOP 21
#define NCAND 32
#define PTK 12

typedef __attribute__((ext_vector_type(8))) __bf16 bf16x8;
typedef __attribute__((ext_vector_type(4))) float f32x4;

// bf16 round-to-nearest-even from fp32 (no NaN handling needed: data is finite)
__device__ __forceinline__ unsigned short f2bf(float x) {
    unsigned u = __float_as_uint(x);
    u += 0x7fffu + ((u >> 16) & 1u);
    return (unsigned short)(u >> 16);
}
__device__ __forceinline__ float bf2f(unsigned short h) {
    return __uint_as_float(((unsigned)h) << 16);
}

// async global->LDS, 16B per lane, wave-uniform LDS base + lane*16
#define GLD16(gp, lp) __builtin_amdgcn_global_load_lds( \
    (const __attribute__((address_space(1))) unsigned int*)(gp), \
    (__attribute__((address_space(3))) unsigned int*)(lp), 16, 0, 0)

// ---------------------------------------------------------------------------
// fp32 SGEMM (unchanged from round 1): used for the 4 small dense GEMMs.
// ---------------------------------------------------------------------------
template<bool TRANSB, int ACT>
__global__ __launch_bounds__(256)
void sgemm128(const float* __restrict__ A, const float* __restrict__ B,
              const float* __restrict__ bias, float* __restrict__ C,
              int M, int N, int K) {
    constexpr int BM = 128, BN = 128, BK = 16;
    __shared__ float As[BK][BM + 4];
    __shared__ float Bs[BK][BN + 4];

    const int tiles_n = N / BN;
    const int by = blockIdx.x / tiles_n;
    const int bx = blockIdx.x % tiles_n;
    const int row0 = by * BM, col0 = bx * BN;
    const int tid = threadIdx.x;
    const int tx = tid & 15, ty = tid >> 4;

    float acc[8][8];
#pragma unroll
    for (int m = 0; m < 8; ++m)
#pragma unroll
        for (int n = 0; n < 8; ++n) acc[m][n] = 0.f;

    for (int k0 = 0; k0 < K; k0 += BK) {
#pragma unroll
        for (int l = 0; l < 2; ++l) {
            int f = tid + l * 256;
            int r = f >> 2, c4 = f & 3;
            float4 v = *reinterpret_cast<const float4*>(
                A + (size_t)(row0 + r) * K + k0 + c4 * 4);
            As[c4 * 4 + 0][r] = v.x;
            As[c4 * 4 + 1][r] = v.y;
            As[c4 * 4 + 2][r] = v.z;
            As[c4 * 4 + 3][r] = v.w;
        }
        if (TRANSB) {
#pragma unroll
            for (int l = 0; l < 2; ++l) {
                int f = tid + l * 256;
                int r = f >> 2, c4 = f & 3;
                float4 v = *reinterpret_cast<const float4*>(
                    B + (size_t)(col0 + r) * K + k0 + c4 * 4);
                Bs[c4 * 4 + 0][r] = v.x;
                Bs[c4 * 4 + 1][r] = v.y;
                Bs[c4 * 4 + 2][r] = v.z;
                Bs[c4 * 4 + 3][r] = v.w;
            }
        } else {
#pragma unroll
            for (int l = 0; l < 2; ++l) {
                int f = tid + l * 256;
                int kr = f >> 5, n4 = f & 31;
                *reinterpret_cast<float4*>(&Bs[kr][n4 * 4]) =
                    *reinterpret_cast<const float4*>(
                        B + (size_t)(k0 + kr) * N + col0 + n4 * 4);
            }
        }
        __syncthreads();

#pragma unroll
        for (int kk = 0; kk < BK; ++kk) {
            float a[8], b[8];
            *(float4*)&a[0] = *(const float4*)&As[kk][ty * 8];
            *(float4*)&a[4] = *(const float4*)&As[kk][ty * 8 + 4];
            *(float4*)&b[0] = *(const float4*)&Bs[kk][tx * 8];
            *(float4*)&b[4] = *(const float4*)&Bs[kk][tx * 8 + 4];
#pragma unroll
            for (int m = 0; m < 8; ++m)
#pragma unroll
                for (int n = 0; n < 8; ++n)
                    acc[m][n] = fmaf(a[m], b[n], acc[m][n]);
        }
        __syncthreads();
    }

    const int crow = row0 + ty * 8;
    const int ccol = col0 + tx * 8;
    float bv[8];
#pragma unroll
    for (int n = 0; n < 8; ++n) bv[n] = bias ? bias[ccol + n] : 0.f;
#pragma unroll
    for (int m = 0; m < 8; ++m) {
        float o[8];
#pragma unroll
        for (int n = 0; n < 8; ++n) {
            float t = acc[m][n] + bv[n];
            if (ACT == 1) t = fmaxf(t, 0.f);
            o[n] = t;
        }
        *reinterpret_cast<float4*>(C + (size_t)(crow + m) * N + ccol)     = *(float4*)&o[0];
        *reinterpret_cast<float4*>(C + (size_t)(crow + m) * N + ccol + 4) = *(float4*)&o[4];
    }
}

// ---------------------------------------------------------------------------
// Row L2-normalize
// ---------------------------------------------------------------------------
__global__ __launch_bounds__(256)
void rownorm_kernel(float* __restrict__ emb) {
    const int row = blockIdx.x, tid = threadIdx.x;
    float* rp = emb + (size_t)row * DD;
    float v0 = rp[tid], v1 = rp[tid + 256];
    float sum = v0 * v0 + v1 * v1;
#pragma unroll
    for (int off = 32; off > 0; off >>= 1) sum += __shfl_down(sum, off, 64);
    __shared__ float ws[4];
    __shared__ float sc_sh;
    if ((tid & 63) == 0) ws[tid >> 6] = sum;
    __syncthreads();
    if (tid == 0) {
        float n = sqrtf(ws[0] + ws[1] + ws[2] + ws[3]);
        sc_sh = 1.0f / fmaxf(n, 1e-12f);
    }
    __syncthreads();
    float sc = sc_sh;
    rp[tid] = v0 * sc;
    rp[tid + 256] = v1 * sc;
}

// ---------------------------------------------------------------------------
// Split fp32 -> (hi, lo) bf16 pair: hi = bf16(x), lo = bf16(x - hi)
// ---------------------------------------------------------------------------
__global__ __launch_bounds__(256)
void split_kernel(const float* __restrict__ e, unsigned short* __restrict__ hi,
                  unsigned short* __restrict__ lo) {
    const int i = (blockIdx.x * 256 + threadIdx.x) * 4;
    float4 v = *reinterpret_cast<const float4*>(e + i);
    ushort4 h, l;
    h.x = f2bf(v.x); l.x = f2bf(v.x - bf2f(h.x));
    h.y = f2bf(v.y); l.y = f2bf(v.y - bf2f(h.y));
    h.z = f2bf(v.z); l.z = f2bf(v.z - bf2f(h.z));
    h.w = f2bf(v.w); l.w = f2bf(v.w - bf2f(h.w));
    *reinterpret_cast<ushort4*>(hi + i) = h;
    *reinterpret_cast<ushort4*>(lo + i) = l;
}

// ---------------------------------------------------------------------------
// sim = E * E^T via bf16x3 MFMA: hi*hi + hi*lo + lo*hi.
// 128x128 tile, BK=32, 4 waves (2x2), 4x4 frags of 16x16x32 per wave.
// LDS staged via global_load_lds width-16 (m97 structure).
// ---------------------------------------------------------------------------
__global__ __launch_bounds__(256)
void simgemm_bf16x3(const unsigned short* __restrict__ Ehi,
                    const unsigned short* __restrict__ Elo,
                    float* __restrict__ C) {
    // XCD-aware swizzle (4096 % 8 == 0 -> simple form is bijective)
    const int bid = blockIdx.x;
    const int swz = (bid & 7) * 512 + (bid >> 3);
    const int by = swz >> 6, bx = swz & 63;

    __shared__ unsigned short Ah[128 * 32];
    __shared__ unsigned short Al[128 * 32];
    __shared__ unsigned short Bh[128 * 32];
    __shared__ unsigned short Bl[128 * 32];

    const int tid = threadIdx.x, lane = tid & 63, wid = tid >> 6;
    const int wm = wid >> 1, wn = wid & 1;
    const int fr = lane & 15, fq = lane >> 4;
    const int lrow = lane >> 2;           // 0..15 within 16-row chunk
    const int lcol8 = (lane & 3) * 8;     // k sub-offset (elements)

    const size_t arow0 = (size_t)by * 128;
    const size_t brow0 = (size_t)bx * 128;

    f32x4 acc[4][4];
#pragma unroll
    for (int m = 0; m < 4; ++m)
#pragma unroll
        for (int n = 0; n < 4; ++n) acc[m][n] = (f32x4){0.f, 0.f, 0.f, 0.f};

    for (int k0 = 0; k0 < DD; k0 += 32) {
        // ---- stage 4 tiles: each wave stages 2 chunks of 16 rows per tile ----
#pragma unroll
        for (int i = 0; i < 2; ++i) {
            const int chunk = wid + i * 4;                // 0..7
            const int grow = chunk * 16 + lrow;           // 0..127
            const size_t goffA = (arow0 + grow) * DD + (k0 + lcol8);
            const size_t goffB = (brow0 + grow) * DD + (k0 + lcol8);
            GLD16(Ehi + goffA, Ah + chunk * 512);
            GLD16(Elo + goffA, Al + chunk * 512);
            GLD16(Ehi + goffB, Bh + chunk * 512);
            GLD16(Elo + goffB, Bl + chunk * 512);
        }
        __syncthreads();

        // ---- fragments: lane holds row (l&15), k = (l>>4)*8 .. +8 ----
        bf16x8 ah[4], al[4], bh[4], bl[4];
#pragma unroll
        for (int mf = 0; mf < 4; ++mf) {
            const int r = wm * 64 + mf * 16 + fr;
            ah[mf] = *(const bf16x8*)&Ah[r * 32 + fq * 8];
            al[mf] = *(const bf16x8*)&Al[r * 32 + fq * 8];
        }
#pragma unroll
        for (int nf = 0; nf < 4; ++nf) {
            const int r = wn * 64 + nf * 16 + fr;
            bh[nf] = *(const bf16x8*)&Bh[r * 32 + fq * 8];
            bl[nf] = *(const bf16x8*)&Bl[r * 32 + fq * 8];
        }
#pragma unroll
        for (int mf = 0; mf < 4; ++mf)
#pragma unroll
            for (int nf = 0; nf < 4; ++nf) {
                acc[mf][nf] = __builtin_amdgcn_mfma_f32_16x16x32_bf16(ah[mf], bh[nf], acc[mf][nf], 0, 0, 0);
                acc[mf][nf] = __builtin_amdgcn_mfma_f32_16x16x32_bf16(ah[mf], bl[nf], acc[mf][nf], 0, 0, 0);
                acc[mf][nf] = __builtin_amdgcn_mfma_f32_16x16x32_bf16(al[mf], bh[nf], acc[mf][nf], 0, 0, 0);
            }
        __syncthreads();
    }

    // ---- epilogue: C/D layout col = lane&15, row = (lane>>4)*4 + reg ----
#pragma unroll
    for (int mf = 0; mf < 4; ++mf) {
#pragma unroll
        for (int nf = 0; nf < 4; ++nf) {
            const size_t row = arow0 + wm * 64 + mf * 16 + fq * 4;
            const int col = bx * 128 + wn * 64 + nf * 16 + fr;
#pragma unroll
            for (int r2 = 0; r2 < 4; ++r2)
                C[(row + r2) * NN + col] = acc[mf][nf][r2];
        }
    }
}

// ---------------------------------------------------------------------------
// Stage 1 top-k: per-row top-NCAND candidate indices from approx sim.
// Per-thread top-PTK register list (PTK=12 over 32 strided elems is
// probabilistically exact for block-wide top-32; P(miss) ~ 1e-20).
// ---------------------------------------------------------------------------
__global__ __launch_bounds__(256)
void topk_cand_kernel(const float* __restrict__ sim, int* __restrict__ cand) {
    const int row = blockIdx.x;
    const int tid = threadIdx.x;
    const float* r = sim + (size_t)row * NN;

    float v[PTK];
    int   id[PTK];
#pragma unroll
    for (int k = 0; k < PTK; ++k) { v[k] = -INFINITY; id[k] = -1; }

    for (int j = tid; j < NN; j += 256) {
        float x = r[j];
        if (x > v[0]) {
#pragma unroll
            for (int k = 0; k < PTK; ++k) {
                if (k < PTK - 1 && x > v[k + 1]) {
                    v[k] = v[k + 1]; id[k] = id[k + 1];
                } else {
                    v[k] = x; id[k] = j;
                    break;
                }
            }
        }
    }

    __shared__ float lv[256][PTK];
    __shared__ int   li[256][PTK];
    __shared__ float rv[256];
    __shared__ int   rt[256];
#pragma unroll
    for (int k = 0; k < PTK; ++k) { lv[tid][k] = v[k]; li[tid][k] = id[k]; }
    int mypos = PTK - 1;
    __syncthreads();

    for (int sel = 0; sel < NCAND; ++sel) {
        rv[tid] = (mypos >= 0) ? lv[tid][mypos] : -INFINITY;
        rt[tid] = tid;
        __syncthreads();
        for (int s = 128; s > 0; s >>= 1) {
            if (tid < s && rv[tid + s] > rv[tid]) {
                rv[tid] = rv[tid + s]; rt[tid] = rt[tid + s];
            }
            __syncthreads();
        }
        if (tid == rt[0]) {
            cand[(size_t)row * NCAND + sel] = li[tid][mypos];
            mypos--;
        }
        __syncthreads();
    }
}

// ---------------------------------------------------------------------------
// Stage 2: exact fp32 refine of the NCAND candidates, select final top-KTOP.
// One block per row, one wave per candidate slice; symmetric bitwise dots.
// ---------------------------------------------------------------------------
__global__ __launch_bounds__(256)
void refine_kernel(const float* __restrict__ emb, const int* __restrict__ cand,
                   int* __restrict__ tidx, float* __restrict__ tval) {
    const int row = blockIdx.x;
    const int tid = threadIdx.x, lane = tid & 63, wv = tid >> 6;
    __shared__ float sval[NCAND];
    __shared__ int   sidx[NCAND];
    const float* ei = emb + (size_t)row * DD;

    float4 a0 = reinterpret_cast<const float4*>(ei)[lane * 2];
    float4 a1 = reinterpret_cast<const float4*>(ei)[lane * 2 + 1];

    for (int c = wv; c < NCAND; c += 4) {
        const int j = cand[(size_t)row * NCAND + c];
        const float* ej = emb + (size_t)j * DD;
        float4 b0 = reinterpret_cast<const float4*>(ej)[lane * 2];
        float4 b1 = reinterpret_cast<const float4*>(ej)[lane * 2 + 1];
        float s = 0.f;
        s = fmaf(a0.x, b0.x, s); s = fmaf(a0.y, b0.y, s);
        s = fmaf(a0.z, b0.z, s); s = fmaf(a0.w, b0.w, s);
        s = fmaf(a1.x, b1.x, s); s = fmaf(a1.y, b1.y, s);
        s = fmaf(a1.z, b1.z, s); s = fmaf(a1.w, b1.w, s);
#pragma unroll
        for (int off = 32; off > 0; off >>= 1) s += __shfl_xor(s, off, 64);
        if (lane == 0) { sval[c] = s; sidx[c] = j; }
    }
    __syncthreads();

    if (tid == 0) {
#pragma unroll 1
        for (int sel = 0; sel < KTOP; ++sel) {
            int best = 0; float bv = sval[0];
#pragma unroll 1
            for (int c = 1; c < NCAND; ++c) {
                float vv = sval[c];
                if (vv > bv || (vv == bv && sidx[c] < sidx[best])) { bv = vv; best = c; }
            }
            tval[(size_t)row * KTOP + sel] = sval[best];
            tidx[(size_t)row * KTOP + sel] = sidx[best];
            sval[best] = -INFINITY;
        }
    }
}

// ---------------------------------------------------------------------------
// Scatter topk edges into adjacency (+ degree accumulation folded in).
// ---------------------------------------------------------------------------
__global__ __launch_bounds__(256)
void scatter_kernel(const int* __restrict__ tidx, const float* __restrict__ tval,
                    float* __restrict__ adj, float* __restrict__ degacc) {
    int t = blockIdx.x * 256 + threadIdx.x;
    if (t >= NN * KTOP) return;
    int i = t / KTOP;
    int j = tidx[t];
    if (j == i || j < 0) return;
    float v = tval[t];
    if (v <= 0.f) return;
    v *= 0.5f;
    atomicAdd(adj + (size_t)i * NN + j, v);
    atomicAdd(adj + (size_t)j * NN + i, v);
    atomicAdd(degacc + i, v);
    atomicAdd(degacc + j, v);
}

__global__ __launch_bounds__(256)
void sdeg_kernel(const float* __restrict__ degacc, float* __restrict__ sdeg) {
    int i = blockIdx.x * 256 + threadIdx.x;
    sdeg[i] = 1.0f / (sqrtf(1.0f + degacc[i]) + 1e-10f);
}

// ---------------------------------------------------------------------------
// SpMM over sparse adjacency rows (ballot-compacted, deterministic).
// ---------------------------------------------------------------------------
template<int COLS, bool DORELU>
__global__ __launch_bounds__(256)
void spmm_kernel(const float* __restrict__ adj, const float* __restrict__ sdeg,
                 const float* __restrict__ X, float* __restrict__ Y) {
    constexpr int CPT = COLS / 256;
    const int i = blockIdx.x;
    const int tid = threadIdx.x;
    const int lane = tid & 63, wave = tid >> 6;

    float acc[CPT];
#pragma unroll
    for (int c = 0; c < CPT; ++c) acc[c] = 0.f;

    __shared__ int   s_j[256];
    __shared__ float s_w[256];
    __shared__ int   s_cnt[4];

    const float si = sdeg[i];
    const float* rowp = adj + (size_t)i * NN;

    for (int j0 = 0; j0 < NN; j0 += 256) {
        float w = rowp[j0 + tid];
        bool nz = (w != 0.f);
        unsigned long long m = __ballot(nz);
        unsigned long long ltmask = (lane == 0) ? 0ull : (~0ull >> (64 - lane));
        int pre = __popcll(m & ltmask);
        if (lane == 0) s_cnt[wave] = __popcll(m);
        __syncthreads();
        int base = 0;
#pragma unroll
        for (int q = 0; q < 4; ++q)
            if (q < wave) base += s_cnt[q];
        int total = s_cnt[0] + s_cnt[1] + s_cnt[2] + s_cnt[3];
        if (nz) {
            int p = base + pre;
            s_j[p] = j0 + tid;
            s_w[p] = w * sdeg[j0 + tid];
        }
        __syncthreads();
        for (int e = 0; e < total; ++e) {
            int j = s_j[e];
            float we = s_w[e];
#pragma unroll
            for (int c = 0; c < CPT; ++c)
                acc[c] += we * X[(size_t)j * COLS + tid + c * 256];
        }
        __syncthreads();
    }

#pragma unroll
    for (int c = 0; c < CPT; ++c) {
        float val = si * (acc[c] + si * X[(size_t)i * COLS + tid + c * 256]);
        if (DORELU) val = fmaxf(val, 0.f);
        Y[(size_t)i * COLS + tid + c * 256] = val;
    }
}

// ---------------------------------------------------------------------------
extern "C" void kernel_launch(void* const* d_in, const int* in_sizes, int n_in,
                              void* d_out, int out_size, void* d_ws, size_t ws_size,
                              hipStream_t stream) {
    const float* features = (const float*)d_in[0];
    const float* masked   = (const float*)d_in[1];
    const float* W1  = (const float*)d_in[2];
    const float* b1  = (const float*)d_in[3];
    const float* W2  = (const float*)d_in[4];
    const float* b2  = (const float*)d_in[5];
    const float* Wg1 = (const float*)d_in[6];
    const float* bg1 = (const float*)d_in[7];
    const float* Wg2 = (const float*)d_in[8];
    const float* bg2 = (const float*)d_in[9];

    float* out_h3  = (float*)d_out;                      // [NN, DD]
    float* out_adj = (float*)d_out + (size_t)NN * DD;    // [NN, NN] (sim scratch too)

    // ws layout (region A = NN*DD floats, region B = NN*DD floats, tail):
    //  region A ("h"): h (fp32) -> hi|lo bf16 (exactly fills it) -> cand -> x2
    //  region B ("emb"): emb -> x1/h1
    float* h    = (float*)d_ws;
    unsigned short* hi = (unsigned short*)h;             // NN*DD bf16
    unsigned short* lo = hi + (size_t)NN * DD;           // NN*DD bf16
    float* emb  = h + (size_t)NN * DD;
    float* tail = emb + (size_t)NN * DD;
    float* tval = tail;                                  // NN*KTOP
    int*   tidx = (int*)(tval + (size_t)NN * KTOP);      // NN*KTOP
    float* degacc = (float*)(tidx + (size_t)NN * KTOP);  // NN
    float* sdeg = degacc + NN;                           // NN
    int*   cand = (int*)h;                               // NN*NCAND (reuses hi/lo space)
    float* x1 = emb;
    float* h1 = emb + (size_t)NN * HH;
    float* x2 = h;

    dim3 blk(256);

    // 1) h = relu(features @ W1 + b1)
    sgemm128<false, 1><<<dim3((NN / 128) * (DD / 128)), blk, 0, stream>>>(
        features, W1, b1, h, NN, DD, DD);
    // 2) emb = h @ W2 + b2
    sgemm128<false, 0><<<dim3((NN / 128) * (DD / 128)), blk, 0, stream>>>(
        h, W2, b2, emb, NN, DD, DD);
    // 3) normalize rows
    rownorm_kernel<<<dim3(NN), blk, 0, stream>>>(emb);
    // 4) split emb -> hi/lo bf16 (into region A; h is dead)
    split_kernel<<<dim3(NN * DD / 1024), blk, 0, stream>>>(emb, hi, lo);
    // 5) approx sim = hi*hi^T + hi*lo^T + lo*hi^T -> out_adj scratch
    simgemm_bf16x3<<<dim3(4096), blk, 0, stream>>>(hi, lo, out_adj);
    // 6) stage-1: top-32 candidate indices per row (cand overwrites hi/lo)
    topk_cand_kernel<<<dim3(NN), blk, 0, stream>>>(out_adj, cand);
    // 7) stage-2: exact fp32 refine + final top-21 selection
    refine_kernel<<<dim3(NN), blk, 0, stream>>>(emb, cand, tidx, tval);
    // 8) zero adjacency + degree accumulator, then scatter (deg folded in)
    hipMemsetAsync(out_adj, 0, (size_t)NN * NN * sizeof(float), stream);
    hipMemsetAsync(degacc, 0, (size_t)NN * sizeof(float), stream);
    scatter_kernel<<<dim3((NN * KTOP + 255) / 256), blk, 0, stream>>>(tidx, tval, out_adj, degacc);
    // 9) sdeg = 1/(sqrt(1+deg)+eps)
    sdeg_kernel<<<dim3(NN / 256), blk, 0, stream>>>(degacc, sdeg);
    // 10) x1 = masked @ Wg1 + bg1   (emb region; emb dead after refine)
    sgemm128<false, 0><<<dim3((NN / 128) * (HH / 128)), blk, 0, stream>>>(
        masked, Wg1, bg1, x1, NN, HH, DD);
    // 11) h1 = relu(Ahat @ x1)
    spmm_kernel<HH, true><<<dim3(NN), blk, 0, stream>>>(out_adj, sdeg, x1, h1);
    // 12) x2 = h1 @ Wg2 + bg2      (region A; cand dead)
    sgemm128<false, 0><<<dim3((NN / 128) * (DD / 128)), blk, 0, stream>>>(
        h1, Wg2, bg2, x2, NN, DD, HH);
    // 13) h3 = Ahat @ x2 -> d_out
    spmm_kernel<DD, false><<<dim3(NN), blk, 0, stream>>>(out_adj, sdeg, x2, out_h3);
}

// Round 3
// 962.062 us; speedup vs baseline: 2.1400x; 1.5889x over previous
//
#include <hip/hip_runtime.h>
#include <cstdint>
#include <cstddef>

#define NN 8192
#define DD 512
#define HH 256
#define KTOP 21
#define CCAP 192   // candidate collection capacity
#define CMIN 32    // minimum candidates (superset of top-32)
#define CEXIT 96   // early-exit upper bound for bisection
#define ECAP 224   // per-row edge-list capacity

typedef __attribute__((ext_vector_type(8))) __bf16 bf16x8;
typedef __attribute__((ext_vector_type(4))) float f32x4;

__device__ __forceinline__ unsigned short f2bf(float x) {
    unsigned u = __float_as_uint(x);
    u += 0x7fffu + ((u >> 16) & 1u);
    return (unsigned short)(u >> 16);
}
__device__ __forceinline__ float bf2f(unsigned short h) {
    return __uint_as_float(((unsigned)h) << 16);
}
// order-preserving key: monotone map float -> uint
__device__ __forceinline__ unsigned ordkey(float x) {
    unsigned b = __float_as_uint(x);
    return b ^ (((int)b >> 31) | 0x80000000u);
}

#define GLD16(gp, lp) __builtin_amdgcn_global_load_lds( \
    (const __attribute__((address_space(1))) unsigned int*)(gp), \
    (__attribute__((address_space(3))) unsigned int*)(lp), 16, 0, 0)

// ---------------------------------------------------------------------------
// fp32 SGEMM (unchanged)
// ---------------------------------------------------------------------------
template<bool TRANSB, int ACT>
__global__ __launch_bounds__(256)
void sgemm128(const float* __restrict__ A, const float* __restrict__ B,
              const float* __restrict__ bias, float* __restrict__ C,
              int M, int N, int K) {
    constexpr int BM = 128, BN = 128, BK = 16;
    __shared__ float As[BK][BM + 4];
    __shared__ float Bs[BK][BN + 4];

    const int tiles_n = N / BN;
    const int by = blockIdx.x / tiles_n;
    const int bx = blockIdx.x % tiles_n;
    const int row0 = by * BM, col0 = bx * BN;
    const int tid = threadIdx.x;
    const int tx = tid & 15, ty = tid >> 4;

    float acc[8][8];
#pragma unroll
    for (int m = 0; m < 8; ++m)
#pragma unroll
        for (int n = 0; n < 8; ++n) acc[m][n] = 0.f;

    for (int k0 = 0; k0 < K; k0 += BK) {
#pragma unroll
        for (int l = 0; l < 2; ++l) {
            int f = tid + l * 256;
            int r = f >> 2, c4 = f & 3;
            float4 v = *reinterpret_cast<const float4*>(
                A + (size_t)(row0 + r) * K + k0 + c4 * 4);
            As[c4 * 4 + 0][r] = v.x;
            As[c4 * 4 + 1][r] = v.y;
            As[c4 * 4 + 2][r] = v.z;
            As[c4 * 4 + 3][r] = v.w;
        }
        if (TRANSB) {
#pragma unroll
            for (int l = 0; l < 2; ++l) {
                int f = tid + l * 256;
                int r = f >> 2, c4 = f & 3;
                float4 v = *reinterpret_cast<const float4*>(
                    B + (size_t)(col0 + r) * K + k0 + c4 * 4);
                Bs[c4 * 4 + 0][r] = v.x;
                Bs[c4 * 4 + 1][r] = v.y;
                Bs[c4 * 4 + 2][r] = v.z;
                Bs[c4 * 4 + 3][r] = v.w;
            }
        } else {
#pragma unroll
            for (int l = 0; l < 2; ++l) {
                int f = tid + l * 256;
                int kr = f >> 5, n4 = f & 31;
                *reinterpret_cast<float4*>(&Bs[kr][n4 * 4]) =
                    *reinterpret_cast<const float4*>(
                        B + (size_t)(k0 + kr) * N + col0 + n4 * 4);
            }
        }
        __syncthreads();

#pragma unroll
        for (int kk = 0; kk < BK; ++kk) {
            float a[8], b[8];
            *(float4*)&a[0] = *(const float4*)&As[kk][ty * 8];
            *(float4*)&a[4] = *(const float4*)&As[kk][ty * 8 + 4];
            *(float4*)&b[0] = *(const float4*)&Bs[kk][tx * 8];
            *(float4*)&b[4] = *(const float4*)&Bs[kk][tx * 8 + 4];
#pragma unroll
            for (int m = 0; m < 8; ++m)
#pragma unroll
                for (int n = 0; n < 8; ++n)
                    acc[m][n] = fmaf(a[m], b[n], acc[m][n]);
        }
        __syncthreads();
    }

    const int crow = row0 + ty * 8;
    const int ccol = col0 + tx * 8;
    float bv[8];
#pragma unroll
    for (int n = 0; n < 8; ++n) bv[n] = bias ? bias[ccol + n] : 0.f;
#pragma unroll
    for (int m = 0; m < 8; ++m) {
        float o[8];
#pragma unroll
        for (int n = 0; n < 8; ++n) {
            float t = acc[m][n] + bv[n];
            if (ACT == 1) t = fmaxf(t, 0.f);
            o[n] = t;
        }
        *reinterpret_cast<float4*>(C + (size_t)(crow + m) * N + ccol)     = *(float4*)&o[0];
        *reinterpret_cast<float4*>(C + (size_t)(crow + m) * N + ccol + 4) = *(float4*)&o[4];
    }
}

// ---------------------------------------------------------------------------
__global__ __launch_bounds__(256)
void rownorm_kernel(float* __restrict__ emb) {
    const int row = blockIdx.x, tid = threadIdx.x;
    float* rp = emb + (size_t)row * DD;
    float v0 = rp[tid], v1 = rp[tid + 256];
    float sum = v0 * v0 + v1 * v1;
#pragma unroll
    for (int off = 32; off > 0; off >>= 1) sum += __shfl_down(sum, off, 64);
    __shared__ float ws[4];
    __shared__ float sc_sh;
    if ((tid & 63) == 0) ws[tid >> 6] = sum;
    __syncthreads();
    if (tid == 0) {
        float n = sqrtf(ws[0] + ws[1] + ws[2] + ws[3]);
        sc_sh = 1.0f / fmaxf(n, 1e-12f);
    }
    __syncthreads();
    float sc = sc_sh;
    rp[tid] = v0 * sc;
    rp[tid + 256] = v1 * sc;
}

// ---------------------------------------------------------------------------
__global__ __launch_bounds__(256)
void split_kernel(const float* __restrict__ e, unsigned short* __restrict__ hi,
                  unsigned short* __restrict__ lo) {
    const int i = (blockIdx.x * 256 + threadIdx.x) * 4;
    float4 v = *reinterpret_cast<const float4*>(e + i);
    ushort4 h, l;
    h.x = f2bf(v.x); l.x = f2bf(v.x - bf2f(h.x));
    h.y = f2bf(v.y); l.y = f2bf(v.y - bf2f(h.y));
    h.z = f2bf(v.z); l.z = f2bf(v.z - bf2f(h.z));
    h.w = f2bf(v.w); l.w = f2bf(v.w - bf2f(h.w));
    *reinterpret_cast<ushort4*>(hi + i) = h;
    *reinterpret_cast<ushort4*>(lo + i) = l;
}

// ---------------------------------------------------------------------------
// sim = E*E^T via bf16x3 MFMA (unchanged from round 2)
// ---------------------------------------------------------------------------
__global__ __launch_bounds__(256)
void simgemm_bf16x3(const unsigned short* __restrict__ Ehi,
                    const unsigned short* __restrict__ Elo,
                    float* __restrict__ C) {
    const int bid = blockIdx.x;
    const int swz = (bid & 7) * 512 + (bid >> 3);
    const int by = swz >> 6, bx = swz & 63;

    __shared__ unsigned short Ah[128 * 32];
    __shared__ unsigned short Al[128 * 32];
    __shared__ unsigned short Bh[128 * 32];
    __shared__ unsigned short Bl[128 * 32];

    const int tid = threadIdx.x, lane = tid & 63, wid = tid >> 6;
    const int wm = wid >> 1, wn = wid & 1;
    const int fr = lane & 15, fq = lane >> 4;
    const int lrow = lane >> 2;
    const int lcol8 = (lane & 3) * 8;

    const size_t arow0 = (size_t)by * 128;
    const size_t brow0 = (size_t)bx * 128;

    f32x4 acc[4][4];
#pragma unroll
    for (int m = 0; m < 4; ++m)
#pragma unroll
        for (int n = 0; n < 4; ++n) acc[m][n] = (f32x4){0.f, 0.f, 0.f, 0.f};

    for (int k0 = 0; k0 < DD; k0 += 32) {
#pragma unroll
        for (int i = 0; i < 2; ++i) {
            const int chunk = wid + i * 4;
            const int grow = chunk * 16 + lrow;
            const size_t goffA = (arow0 + grow) * DD + (k0 + lcol8);
            const size_t goffB = (brow0 + grow) * DD + (k0 + lcol8);
            GLD16(Ehi + goffA, Ah + chunk * 512);
            GLD16(Elo + goffA, Al + chunk * 512);
            GLD16(Ehi + goffB, Bh + chunk * 512);
            GLD16(Elo + goffB, Bl + chunk * 512);
        }
        __syncthreads();

        bf16x8 ah[4], al[4], bh[4], bl[4];
#pragma unroll
        for (int mf = 0; mf < 4; ++mf) {
            const int r = wm * 64 + mf * 16 + fr;
            ah[mf] = *(const bf16x8*)&Ah[r * 32 + fq * 8];
            al[mf] = *(const bf16x8*)&Al[r * 32 + fq * 8];
        }
#pragma unroll
        for (int nf = 0; nf < 4; ++nf) {
            const int r = wn * 64 + nf * 16 + fr;
            bh[nf] = *(const bf16x8*)&Bh[r * 32 + fq * 8];
            bl[nf] = *(const bf16x8*)&Bl[r * 32 + fq * 8];
        }
#pragma unroll
        for (int mf = 0; mf < 4; ++mf)
#pragma unroll
            for (int nf = 0; nf < 4; ++nf) {
                acc[mf][nf] = __builtin_amdgcn_mfma_f32_16x16x32_bf16(ah[mf], bh[nf], acc[mf][nf], 0, 0, 0);
                acc[mf][nf] = __builtin_amdgcn_mfma_f32_16x16x32_bf16(ah[mf], bl[nf], acc[mf][nf], 0, 0, 0);
                acc[mf][nf] = __builtin_amdgcn_mfma_f32_16x16x32_bf16(al[mf], bh[nf], acc[mf][nf], 0, 0, 0);
            }
        __syncthreads();
    }

#pragma unroll
    for (int mf = 0; mf < 4; ++mf) {
#pragma unroll
        for (int nf = 0; nf < 4; ++nf) {
            const size_t row = arow0 + wm * 64 + mf * 16 + fq * 4;
            const int col = bx * 128 + wn * 64 + nf * 16 + fr;
#pragma unroll
            for (int r2 = 0; r2 < 4; ++r2)
                C[(row + r2) * NN + col] = acc[mf][nf][r2];
        }
    }
}

// ---------------------------------------------------------------------------
// Top-candidate selection via uniform binary search on the ordered-key value.
// Finds t with count(>= t) in [CMIN, CEXIT] (exact fallback after 32 iters),
// collects indices >= t. Set is deterministic; order doesn't matter.
// ---------------------------------------------------------------------------
__global__ __launch_bounds__(256)
void topk_cand_kernel(const float* __restrict__ sim, int* __restrict__ cand,
                      int* __restrict__ ccnt) {
    const int row = blockIdx.x;
    const int tid = threadIdx.x;
    const int lane = tid & 63, wave = tid >> 6;
    const float4* rp = reinterpret_cast<const float4*>(sim + (size_t)row * NN);

    unsigned key[32];
#pragma unroll
    for (int u = 0; u < 8; ++u) {
        float4 v = rp[u * 256 + tid];
        key[u * 4 + 0] = ordkey(v.x);
        key[u * 4 + 1] = ordkey(v.y);
        key[u * 4 + 2] = ordkey(v.z);
        key[u * 4 + 3] = ordkey(v.w);
    }

    __shared__ int s_part[2][4];
    __shared__ int s_pos;
    int parity = 0;

    auto blockCount = [&](unsigned thr) -> int {
        int c = 0;
#pragma unroll
        for (int i = 0; i < 32; ++i) c += (key[i] >= thr) ? 1 : 0;
#pragma unroll
        for (int off = 32; off > 0; off >>= 1) c += __shfl_down(c, off, 64);
        if (lane == 0) s_part[parity & 1][wave] = c;
        __syncthreads();
        int tot = s_part[parity & 1][0] + s_part[parity & 1][1] +
                  s_part[parity & 1][2] + s_part[parity & 1][3];
        parity++;
        return tot;
    };

    unsigned lo = 0u, hi = 0xFFFFFFFFu;
    unsigned tfin = 0u;
    int cfin = -1;
    for (int it = 0; it < 33 && lo < hi; ++it) {
        unsigned mid = lo + ((hi - lo) >> 1) + 1u;
        int c = blockCount(mid);
        if (c >= CMIN) {
            lo = mid;
            if (c <= CEXIT) { tfin = mid; cfin = c; break; }
        } else {
            hi = mid - 1u;
        }
    }
    if (cfin < 0) { tfin = lo; cfin = blockCount(lo); }

    if (tid == 0) s_pos = 0;
    __syncthreads();
#pragma unroll
    for (int u = 0; u < 8; ++u) {
#pragma unroll
        for (int w = 0; w < 4; ++w) {
            if (key[u * 4 + w] >= tfin) {
                int pos = atomicAdd(&s_pos, 1);
                if (pos < CCAP)
                    cand[(size_t)row * CCAP + pos] = (u * 256 + tid) * 4 + w;
            }
        }
    }
    __syncthreads();
    if (tid == 0) ccnt[row] = min(s_pos, CCAP);
}

// ---------------------------------------------------------------------------
// Exact fp32 refine of candidates, final top-21 by (value desc, idx asc).
// ---------------------------------------------------------------------------
__global__ __launch_bounds__(256)
void refine_kernel(const float* __restrict__ emb, const int* __restrict__ cand,
                   const int* __restrict__ ccnt,
                   int* __restrict__ tidx, float* __restrict__ tval) {
    const int row = blockIdx.x;
    const int tid = threadIdx.x, lane = tid & 63, wv = tid >> 6;
    const int cnt = ccnt[row];
    __shared__ float sval[CCAP];
    __shared__ int   sidx[CCAP];
    const float* ei = emb + (size_t)row * DD;

    float4 a0 = reinterpret_cast<const float4*>(ei)[lane * 2];
    float4 a1 = reinterpret_cast<const float4*>(ei)[lane * 2 + 1];

    // two candidates in flight per wave for latency overlap
    for (int base = wv * 2; base < cnt; base += 8) {
#pragma unroll
        for (int q = 0; q < 2; ++q) {
            int c = base + q;
            if (c >= cnt) break;
            const int j = cand[(size_t)row * CCAP + c];
            const float* ej = emb + (size_t)j * DD;
            float4 b0 = reinterpret_cast<const float4*>(ej)[lane * 2];
            float4 b1 = reinterpret_cast<const float4*>(ej)[lane * 2 + 1];
            float s = 0.f;
            s = fmaf(a0.x, b0.x, s); s = fmaf(a0.y, b0.y, s);
            s = fmaf(a0.z, b0.z, s); s = fmaf(a0.w, b0.w, s);
            s = fmaf(a1.x, b1.x, s); s = fmaf(a1.y, b1.y, s);
            s = fmaf(a1.z, b1.z, s); s = fmaf(a1.w, b1.w, s);
#pragma unroll
            for (int off = 32; off > 0; off >>= 1) s += __shfl_xor(s, off, 64);
            if (lane == 0) { sval[c] = s; sidx[c] = j; }
        }
    }
    __syncthreads();

    if (wv == 0) {
        // register-resident selection: lane covers slots lane, lane+64, lane+128
        float v[3]; int id[3];
#pragma unroll
        for (int k = 0; k < 3; ++k) {
            int s = lane + 64 * k;
            if (s < cnt) { v[k] = sval[s]; id[k] = sidx[s]; }
            else         { v[k] = -INFINITY; id[k] = 0x7fffffff; }
        }
#pragma unroll 1
        for (int sel = 0; sel < KTOP; ++sel) {
            float bv = v[0]; int bi = id[0];
#pragma unroll
            for (int k = 1; k < 3; ++k)
                if (v[k] > bv || (v[k] == bv && id[k] < bi)) { bv = v[k]; bi = id[k]; }
#pragma unroll
            for (int off = 1; off < 64; off <<= 1) {
                float ov = __shfl_xor(bv, off, 64);
                int   oi = __shfl_xor(bi, off, 64);
                if (ov > bv || (ov == bv && oi < bi)) { bv = ov; bi = oi; }
            }
            if (lane == 0) {
                tval[(size_t)row * KTOP + sel] = bv;
                tidx[(size_t)row * KTOP + sel] = bi;
            }
#pragma unroll
            for (int k = 0; k < 3; ++k)
                if (id[k] == bi) { v[k] = -INFINITY; id[k] = 0x7fffffff; }
        }
    }
}

// ---------------------------------------------------------------------------
// Scatter edges into dense adj (2-addend atomics = deterministic) and build
// per-row edge lists (order nondeterministic; sorted next kernel).
// ---------------------------------------------------------------------------
__global__ __launch_bounds__(256)
void scatter_kernel(const int* __restrict__ tidx, const float* __restrict__ tval,
                    float* __restrict__ adj, int* __restrict__ ecnt,
                    int* __restrict__ ej, float* __restrict__ ev) {
    int t = blockIdx.x * 256 + threadIdx.x;
    if (t >= NN * KTOP) return;
    int i = t / KTOP;
    int j = tidx[t];
    if (j == i || j < 0) return;
    float v = tval[t];
    if (v <= 0.f) return;
    v *= 0.5f;
    atomicAdd(adj + (size_t)i * NN + j, v);
    atomicAdd(adj + (size_t)j * NN + i, v);
    int pi = atomicAdd(ecnt + i, 1);
    if (pi < ECAP) { ej[(size_t)i * ECAP + pi] = j; ev[(size_t)i * ECAP + pi] = v; }
    int pj = atomicAdd(ecnt + j, 1);
    if (pj < ECAP) { ej[(size_t)j * ECAP + pj] = i; ev[(size_t)j * ECAP + pj] = v; }
}

// ---------------------------------------------------------------------------
// Sort each row's edge list by (j, valbits) -> deterministic order; compute
// sdeg. Overflow rows: deterministic dense-row scan for degree.
// ---------------------------------------------------------------------------
__global__ __launch_bounds__(256)
void sortdeg_kernel(int* __restrict__ ej, float* __restrict__ ev,
                    const int* __restrict__ ecnt, const float* __restrict__ adj,
                    float* __restrict__ sdeg) {
    const int row = blockIdx.x, tid = threadIdx.x;
    const int lane = tid & 63, wave = tid >> 6;
    const int nraw = ecnt[row];
    __shared__ float ws[4];

    if (nraw > ECAP) {
        // dense fallback: fixed-shape deterministic reduction
        const float4* rp = reinterpret_cast<const float4*>(adj + (size_t)row * NN);
        float sum = 0.f;
        for (int f = tid; f < NN / 4; f += 256) {
            float4 v = rp[f];
            sum += (v.x + v.y) + (v.z + v.w);
        }
#pragma unroll
        for (int off = 32; off > 0; off >>= 1) sum += __shfl_down(sum, off, 64);
        if (lane == 0) ws[wave] = sum;
        __syncthreads();
        if (tid == 0)
            sdeg[row] = 1.0f / (sqrtf(1.0f + ws[0] + ws[1] + ws[2] + ws[3]) + 1e-10f);
        return;
    }

    const int n = nraw;
    __shared__ int   lj[ECAP];
    __shared__ float lv[ECAP];
    __shared__ unsigned long long skey[ECAP];
    __shared__ int   oj[ECAP];
    __shared__ float ov[ECAP];
    if (tid < n) {
        int  jv = ej[(size_t)row * ECAP + tid];
        float vv = ev[(size_t)row * ECAP + tid];
        lj[tid] = jv; lv[tid] = vv;
        skey[tid] = ((unsigned long long)(unsigned)jv << 32) | (unsigned long long)ordkey(vv);
    }
    __syncthreads();
    if (tid < n) {
        unsigned long long mk = skey[tid];
        int rank = 0;
        for (int u = 0; u < n; ++u) {
            unsigned long long ku = skey[u];
            rank += (ku < mk || (ku == mk && u < tid)) ? 1 : 0;
        }
        oj[rank] = lj[tid];
        ov[rank] = lv[tid];
    }
    __syncthreads();
    if (tid < n) {
        ej[(size_t)row * ECAP + tid] = oj[tid];
        ev[(size_t)row * ECAP + tid] = ov[tid];
    }
    if (tid == 0) {
        float deg = 1.0f;
        for (int e = 0; e < n; ++e) deg += ov[e];
        sdeg[row] = 1.0f / (sqrtf(deg) + 1e-10f);
    }
}

// ---------------------------------------------------------------------------
// SpMM from sorted edge lists (deterministic); dense-scan fallback on ovf.
// ---------------------------------------------------------------------------
template<int COLS, bool DORELU>
__global__ __launch_bounds__(256)
void spmm_edges(const int* __restrict__ ej, const float* __restrict__ ev,
                const int* __restrict__ ecnt, const float* __restrict__ adj,
                const float* __restrict__ sdeg,
                const float* __restrict__ X, float* __restrict__ Y) {
    constexpr int CPT = COLS / 256;
    const int i = blockIdx.x;
    const int tid = threadIdx.x;
    const int lane = tid & 63, wave = tid >> 6;
    const float si = sdeg[i];
    const int nraw = ecnt[i];

    float acc[CPT];
#pragma unroll
    for (int c = 0; c < CPT; ++c) acc[c] = 0.f;

    if (nraw <= ECAP) {
        __shared__ int   s_j[ECAP];
        __shared__ float s_w[ECAP];
        if (tid < nraw) {
            int j = ej[(size_t)i * ECAP + tid];
            s_j[tid] = j;
            s_w[tid] = ev[(size_t)i * ECAP + tid] * sdeg[j];
        }
        __syncthreads();
#pragma unroll 4
        for (int e = 0; e < nraw; ++e) {
            int j = s_j[e];
            float we = s_w[e];
#pragma unroll
            for (int c = 0; c < CPT; ++c)
                acc[c] += we * X[(size_t)j * COLS + tid + c * 256];
        }
    } else {
        __shared__ int   s_j[256];
        __shared__ float s_w[256];
        __shared__ int   s_cnt[4];
        const float* rowp = adj + (size_t)i * NN;
        for (int j0 = 0; j0 < NN; j0 += 256) {
            float w = rowp[j0 + tid];
            bool nz = (w != 0.f);
            unsigned long long m = __ballot(nz);
            unsigned long long ltmask = (lane == 0) ? 0ull : (~0ull >> (64 - lane));
            int pre = __popcll(m & ltmask);
            if (lane == 0) s_cnt[wave] = __popcll(m);
            __syncthreads();
            int base = 0;
#pragma unroll
            for (int q = 0; q < 4; ++q)
                if (q < wave) base += s_cnt[q];
            int total = s_cnt[0] + s_cnt[1] + s_cnt[2] + s_cnt[3];
            if (nz) {
                int p = base + pre;
                s_j[p] = j0 + tid;
                s_w[p] = w * sdeg[j0 + tid];
            }
            __syncthreads();
            for (int e = 0; e < total; ++e) {
                int j = s_j[e];
                float we = s_w[e];
#pragma unroll
                for (int c = 0; c < CPT; ++c)
                    acc[c] += we * X[(size_t)j * COLS + tid + c * 256];
            }
            __syncthreads();
        }
    }

#pragma unroll
    for (int c = 0; c < CPT; ++c) {
        float val = si * (acc[c] + si * X[(size_t)i * COLS + tid + c * 256]);
        if (DORELU) val = fmaxf(val, 0.f);
        Y[(size_t)i * COLS + tid + c * 256] = val;
    }
}

// ---------------------------------------------------------------------------
extern "C" void kernel_launch(void* const* d_in, const int* in_sizes, int n_in,
                              void* d_out, int out_size, void* d_ws, size_t ws_size,
                              hipStream_t stream) {
    const float* features = (const float*)d_in[0];
    const float* masked   = (const float*)d_in[1];
    const float* W1  = (const float*)d_in[2];
    const float* b1  = (const float*)d_in[3];
    const float* W2  = (const float*)d_in[4];
    const float* b2  = (const float*)d_in[5];
    const float* Wg1 = (const float*)d_in[6];
    const float* bg1 = (const float*)d_in[7];
    const float* Wg2 = (const float*)d_in[8];
    const float* bg2 = (const float*)d_in[9];

    float* out_h3  = (float*)d_out;                      // [NN, DD]
    float* out_adj = (float*)d_out + (size_t)NN * DD;    // [NN, NN] (sim scratch too)

    // ws layout:
    //  region A (NN*DD f32): h -> hi|lo bf16 -> cand (NN*CCAP int) -> x2
    //  region B (NN*DD f32): emb -> x1/h1
    //  tail: tval, tidx, sdeg, ecnt, ccnt, elist_j, elist_v
    float* h    = (float*)d_ws;
    unsigned short* hi = (unsigned short*)h;
    unsigned short* lo = hi + (size_t)NN * DD;
    float* emb  = h + (size_t)NN * DD;
    float* tail = emb + (size_t)NN * DD;
    float* tval = tail;                                   // NN*KTOP
    int*   tidx = (int*)(tval + (size_t)NN * KTOP);       // NN*KTOP
    float* sdeg = (float*)(tidx + (size_t)NN * KTOP);     // NN
    int*   ecnt = (int*)(sdeg + NN);                      // NN
    int*   ccnt = ecnt + NN;                              // NN
    int*   elj  = ccnt + NN;                              // NN*ECAP
    float* elv  = (float*)(elj + (size_t)NN * ECAP);      // NN*ECAP
    int*   cand = (int*)h;                                // NN*CCAP (overlays hi/lo)
    float* x1 = emb;
    float* h1 = emb + (size_t)NN * HH;
    float* x2 = h;

    dim3 blk(256);

    sgemm128<false, 1><<<dim3((NN / 128) * (DD / 128)), blk, 0, stream>>>(
        features, W1, b1, h, NN, DD, DD);
    sgemm128<false, 0><<<dim3((NN / 128) * (DD / 128)), blk, 0, stream>>>(
        h, W2, b2, emb, NN, DD, DD);
    rownorm_kernel<<<dim3(NN), blk, 0, stream>>>(emb);
    split_kernel<<<dim3(NN * DD / 1024), blk, 0, stream>>>(emb, hi, lo);
    simgemm_bf16x3<<<dim3(4096), blk, 0, stream>>>(hi, lo, out_adj);
    topk_cand_kernel<<<dim3(NN), blk, 0, stream>>>(out_adj, cand, ccnt);
    refine_kernel<<<dim3(NN), blk, 0, stream>>>(emb, cand, ccnt, tidx, tval);
    hipMemsetAsync(out_adj, 0, (size_t)NN * NN * sizeof(float), stream);
    hipMemsetAsync(ecnt, 0, (size_t)NN * sizeof(int), stream);
    scatter_kernel<<<dim3((NN * KTOP + 255) / 256), blk, 0, stream>>>(
        tidx, tval, out_adj, ecnt, elj, elv);
    sortdeg_kernel<<<dim3(NN), blk, 0, stream>>>(elj, elv, ecnt, out_adj, sdeg);
    sgemm128<false, 0><<<dim3((NN / 128) * (HH / 128)), blk, 0, stream>>>(
        masked, Wg1, bg1, x1, NN, HH, DD);
    spmm_edges<HH, true><<<dim3(NN), blk, 0, stream>>>(
        elj, elv, ecnt, out_adj, sdeg, x1, h1);
    sgemm128<false, 0><<<dim3((NN / 128) * (DD / 128)), blk, 0, stream>>>(
        h1, Wg2, bg2, x2, NN, DD, HH);
    spmm_edges<DD, false><<<dim3(NN), blk, 0, stream>>>(
        elj, elv, ecnt, out_adj, sdeg, x2, out_h3);
}

// Round 4
// 802.128 us; speedup vs baseline: 2.5667x; 1.1994x over previous
//
#include <hip/hip_runtime.h>
#include <cstdint>
#include <cstddef>

#define NN 8192
#define DD 512
#define HH 256
#define KTOP 21
#define CCAP 192   // candidate collection capacity
#define CMIN 48    // minimum candidates (superset of top-21 w/ bf16 margin)
#define ECAP 224   // per-row edge-list capacity
#define NBIN 1024

typedef __attribute__((ext_vector_type(8))) __bf16 bf16x8;
typedef __attribute__((ext_vector_type(4))) float f32x4;

__device__ __forceinline__ unsigned short f2bf(float x) {
    unsigned u = __float_as_uint(x);
    u += 0x7fffu + ((u >> 16) & 1u);
    return (unsigned short)(u >> 16);
}
__device__ __forceinline__ float bf2f(unsigned short h) {
    return __uint_as_float(((unsigned)h) << 16);
}
// order-preserving key: monotone map float -> uint (used by sortdeg)
__device__ __forceinline__ unsigned ordkey(float x) {
    unsigned b = __float_as_uint(x);
    return b ^ (((int)b >> 31) | 0x80000000u);
}

#define GLD16(gp, lp) __builtin_amdgcn_global_load_lds( \
    (const __attribute__((address_space(1))) unsigned int*)(gp), \
    (__attribute__((address_space(3))) unsigned int*)(lp), 16, 0, 0)

// ---------------------------------------------------------------------------
// fp32 SGEMM (unchanged)
// ---------------------------------------------------------------------------
template<bool TRANSB, int ACT>
__global__ __launch_bounds__(256)
void sgemm128(const float* __restrict__ A, const float* __restrict__ B,
              const float* __restrict__ bias, float* __restrict__ C,
              int M, int N, int K) {
    constexpr int BM = 128, BN = 128, BK = 16;
    __shared__ float As[BK][BM + 4];
    __shared__ float Bs[BK][BN + 4];

    const int tiles_n = N / BN;
    const int by = blockIdx.x / tiles_n;
    const int bx = blockIdx.x % tiles_n;
    const int row0 = by * BM, col0 = bx * BN;
    const int tid = threadIdx.x;
    const int tx = tid & 15, ty = tid >> 4;

    float acc[8][8];
#pragma unroll
    for (int m = 0; m < 8; ++m)
#pragma unroll
        for (int n = 0; n < 8; ++n) acc[m][n] = 0.f;

    for (int k0 = 0; k0 < K; k0 += BK) {
#pragma unroll
        for (int l = 0; l < 2; ++l) {
            int f = tid + l * 256;
            int r = f >> 2, c4 = f & 3;
            float4 v = *reinterpret_cast<const float4*>(
                A + (size_t)(row0 + r) * K + k0 + c4 * 4);
            As[c4 * 4 + 0][r] = v.x;
            As[c4 * 4 + 1][r] = v.y;
            As[c4 * 4 + 2][r] = v.z;
            As[c4 * 4 + 3][r] = v.w;
        }
        if (TRANSB) {
#pragma unroll
            for (int l = 0; l < 2; ++l) {
                int f = tid + l * 256;
                int r = f >> 2, c4 = f & 3;
                float4 v = *reinterpret_cast<const float4*>(
                    B + (size_t)(col0 + r) * K + k0 + c4 * 4);
                Bs[c4 * 4 + 0][r] = v.x;
                Bs[c4 * 4 + 1][r] = v.y;
                Bs[c4 * 4 + 2][r] = v.z;
                Bs[c4 * 4 + 3][r] = v.w;
            }
        } else {
#pragma unroll
            for (int l = 0; l < 2; ++l) {
                int f = tid + l * 256;
                int kr = f >> 5, n4 = f & 31;
                *reinterpret_cast<float4*>(&Bs[kr][n4 * 4]) =
                    *reinterpret_cast<const float4*>(
                        B + (size_t)(k0 + kr) * N + col0 + n4 * 4);
            }
        }
        __syncthreads();

#pragma unroll
        for (int kk = 0; kk < BK; ++kk) {
            float a[8], b[8];
            *(float4*)&a[0] = *(const float4*)&As[kk][ty * 8];
            *(float4*)&a[4] = *(const float4*)&As[kk][ty * 8 + 4];
            *(float4*)&b[0] = *(const float4*)&Bs[kk][tx * 8];
            *(float4*)&b[4] = *(const float4*)&Bs[kk][tx * 8 + 4];
#pragma unroll
            for (int m = 0; m < 8; ++m)
#pragma unroll
                for (int n = 0; n < 8; ++n)
                    acc[m][n] = fmaf(a[m], b[n], acc[m][n]);
        }
        __syncthreads();
    }

    const int crow = row0 + ty * 8;
    const int ccol = col0 + tx * 8;
    float bv[8];
#pragma unroll
    for (int n = 0; n < 8; ++n) bv[n] = bias ? bias[ccol + n] : 0.f;
#pragma unroll
    for (int m = 0; m < 8; ++m) {
        float o[8];
#pragma unroll
        for (int n = 0; n < 8; ++n) {
            float t = acc[m][n] + bv[n];
            if (ACT == 1) t = fmaxf(t, 0.f);
            o[n] = t;
        }
        *reinterpret_cast<float4*>(C + (size_t)(crow + m) * N + ccol)     = *(float4*)&o[0];
        *reinterpret_cast<float4*>(C + (size_t)(crow + m) * N + ccol + 4) = *(float4*)&o[4];
    }
}

// ---------------------------------------------------------------------------
__global__ __launch_bounds__(256)
void rownorm_kernel(float* __restrict__ emb) {
    const int row = blockIdx.x, tid = threadIdx.x;
    float* rp = emb + (size_t)row * DD;
    float v0 = rp[tid], v1 = rp[tid + 256];
    float sum = v0 * v0 + v1 * v1;
#pragma unroll
    for (int off = 32; off > 0; off >>= 1) sum += __shfl_down(sum, off, 64);
    __shared__ float ws[4];
    __shared__ float sc_sh;
    if ((tid & 63) == 0) ws[tid >> 6] = sum;
    __syncthreads();
    if (tid == 0) {
        float n = sqrtf(ws[0] + ws[1] + ws[2] + ws[3]);
        sc_sh = 1.0f / fmaxf(n, 1e-12f);
    }
    __syncthreads();
    float sc = sc_sh;
    rp[tid] = v0 * sc;
    rp[tid + 256] = v1 * sc;
}

// ---------------------------------------------------------------------------
// Cast fp32 -> bf16 (RNE), hi only.
// ---------------------------------------------------------------------------
__global__ __launch_bounds__(256)
void cast_bf16_kernel(const float* __restrict__ e, unsigned short* __restrict__ hi) {
    const int i = (blockIdx.x * 256 + threadIdx.x) * 4;
    float4 v = *reinterpret_cast<const float4*>(e + i);
    ushort4 h;
    h.x = f2bf(v.x); h.y = f2bf(v.y); h.z = f2bf(v.z); h.w = f2bf(v.w);
    *reinterpret_cast<ushort4*>(hi + i) = h;
}

// ---------------------------------------------------------------------------
// approx sim = Ehi * Ehi^T (single bf16 MFMA product), output stored as bf16.
// 128x128 tile, BK=32, 4 waves (2x2), 4x4 frags of 16x16x32 per wave.
// ---------------------------------------------------------------------------
__global__ __launch_bounds__(256)
void simgemm_bf16(const unsigned short* __restrict__ Ehi,
                  unsigned short* __restrict__ Cb) {
    const int bid = blockIdx.x;
    const int swz = (bid & 7) * 512 + (bid >> 3);
    const int by = swz >> 6, bx = swz & 63;

    __shared__ unsigned short Ah[128 * 32];
    __shared__ unsigned short Bh[128 * 32];

    const int tid = threadIdx.x, lane = tid & 63, wid = tid >> 6;
    const int wm = wid >> 1, wn = wid & 1;
    const int fr = lane & 15, fq = lane >> 4;
    const int lrow = lane >> 2;
    const int lcol8 = (lane & 3) * 8;

    const size_t arow0 = (size_t)by * 128;
    const size_t brow0 = (size_t)bx * 128;

    f32x4 acc[4][4];
#pragma unroll
    for (int m = 0; m < 4; ++m)
#pragma unroll
        for (int n = 0; n < 4; ++n) acc[m][n] = (f32x4){0.f, 0.f, 0.f, 0.f};

    for (int k0 = 0; k0 < DD; k0 += 32) {
#pragma unroll
        for (int i = 0; i < 2; ++i) {
            const int chunk = wid + i * 4;
            const int grow = chunk * 16 + lrow;
            GLD16(Ehi + (arow0 + grow) * DD + (k0 + lcol8), Ah + chunk * 512);
            GLD16(Ehi + (brow0 + grow) * DD + (k0 + lcol8), Bh + chunk * 512);
        }
        __syncthreads();

        bf16x8 ah[4], bh[4];
#pragma unroll
        for (int mf = 0; mf < 4; ++mf)
            ah[mf] = *(const bf16x8*)&Ah[(wm * 64 + mf * 16 + fr) * 32 + fq * 8];
#pragma unroll
        for (int nf = 0; nf < 4; ++nf)
            bh[nf] = *(const bf16x8*)&Bh[(wn * 64 + nf * 16 + fr) * 32 + fq * 8];
#pragma unroll
        for (int mf = 0; mf < 4; ++mf)
#pragma unroll
            for (int nf = 0; nf < 4; ++nf)
                acc[mf][nf] = __builtin_amdgcn_mfma_f32_16x16x32_bf16(ah[mf], bh[nf], acc[mf][nf], 0, 0, 0);
        __syncthreads();
    }

#pragma unroll
    for (int mf = 0; mf < 4; ++mf) {
#pragma unroll
        for (int nf = 0; nf < 4; ++nf) {
            const size_t row = arow0 + wm * 64 + mf * 16 + fq * 4;
            const int col = bx * 128 + wn * 64 + nf * 16 + fr;
#pragma unroll
            for (int r2 = 0; r2 < 4; ++r2)
                Cb[(row + r2) * NN + col] = f2bf(acc[mf][nf][r2]);
        }
    }
}

// ---------------------------------------------------------------------------
// One-pass histogram top-candidate selection on bf16 sim.
// Values in [0,1] (diag=1); bins = clamp(v*1024). Find largest bin b* with
// suffix-count >= CMIN; collect all elems with bin >= b* via deterministic
// prefix-sum compaction.
// ---------------------------------------------------------------------------
__global__ __launch_bounds__(256)
void topk_cand_kernel(const unsigned short* __restrict__ simb,
                      int* __restrict__ cand, int* __restrict__ ccnt) {
    const int row = blockIdx.x;
    const int tid = threadIdx.x;
    const int lane = tid & 63, wave = tid >> 6;
    const uint4* rp = reinterpret_cast<const uint4*>(simb + (size_t)row * NN);

    // 4 x uint4 = 16 uints = 32 bf16 values
    uint4 q[4];
#pragma unroll
    for (int t = 0; t < 4; ++t) q[t] = rp[t * 256 + tid];
    unsigned pk[16];
#pragma unroll
    for (int t = 0; t < 4; ++t) {
        pk[t * 4 + 0] = q[t].x; pk[t * 4 + 1] = q[t].y;
        pk[t * 4 + 2] = q[t].z; pk[t * 4 + 3] = q[t].w;
    }

    __shared__ int hist[NBIN];
    for (int b = tid; b < NBIN; b += 256) hist[b] = 0;
    __syncthreads();

    short bins[32];
#pragma unroll
    for (int u = 0; u < 16; ++u) {
        float flo = __uint_as_float(pk[u] << 16);
        float fhi = __uint_as_float(pk[u] & 0xFFFF0000u);
        int blo = (int)(flo * (float)NBIN); blo = max(0, min(NBIN - 1, blo));
        int bhi = (int)(fhi * (float)NBIN); bhi = max(0, min(NBIN - 1, bhi));
        bins[u * 2]     = (short)blo;
        bins[u * 2 + 1] = (short)bhi;
        atomicAdd(&hist[blo], 1);
        atomicAdd(&hist[bhi], 1);
    }
    __syncthreads();

    // wave 0: suffix scan from top bin, find b*
    __shared__ int s_bstar;
    if (wave == 0) {
        int cum = 0, found = -1;
        for (int c0 = NBIN - 1; c0 >= 0 && found < 0; c0 -= 64) {
            int b = c0 - lane;
            int cnt = (b >= 0) ? hist[b] : 0;
            int sc = cnt;
#pragma unroll
            for (int off = 1; off < 64; off <<= 1) {
                int o = __shfl_up(sc, off, 64);
                if (lane >= off) sc += o;
            }
            int chunk_total = __shfl(sc, 63, 64);
            bool hit = (cum + sc >= CMIN);
            unsigned long long mh = __ballot(hit);
            if (mh) found = c0 - (__ffsll((long long)mh) - 1);
            else cum += chunk_total;
        }
        if (found < 0) found = 0;
        if (lane == 0) s_bstar = found;
    }
    __syncthreads();
    const int bstar = s_bstar;

    // deterministic compaction: per-thread count -> block prefix -> write
    int cnt = 0;
#pragma unroll
    for (int i = 0; i < 32; ++i) cnt += (bins[i] >= bstar) ? 1 : 0;
    int sc = cnt;
#pragma unroll
    for (int off = 1; off < 64; off <<= 1) {
        int o = __shfl_up(sc, off, 64);
        if (lane >= off) sc += o;
    }
    __shared__ int wtot[4];
    if (lane == 63) wtot[wave] = sc;
    __syncthreads();
    int base = sc - cnt;
#pragma unroll
    for (int w = 0; w < 4; ++w)
        if (w < wave) base += wtot[w];
    int total = wtot[0] + wtot[1] + wtot[2] + wtot[3];

    int pos = base;
#pragma unroll
    for (int u = 0; u < 16; ++u) {
#pragma unroll
        for (int h = 0; h < 2; ++h) {
            if (bins[u * 2 + h] >= bstar) {
                if (pos < CCAP) {
                    int col = ((u >> 2) * 256 + tid) * 8 + (u & 3) * 2 + h;
                    cand[(size_t)row * CCAP + pos] = col;
                }
                pos++;
            }
        }
    }
    if (tid == 0) ccnt[row] = min(total, CCAP);
}

// ---------------------------------------------------------------------------
// Exact fp32 refine of candidates, final top-21 by (value desc, idx asc).
// ---------------------------------------------------------------------------
__global__ __launch_bounds__(256)
void refine_kernel(const float* __restrict__ emb, const int* __restrict__ cand,
                   const int* __restrict__ ccnt,
                   int* __restrict__ tidx, float* __restrict__ tval) {
    const int row = blockIdx.x;
    const int tid = threadIdx.x, lane = tid & 63, wv = tid >> 6;
    const int cnt = ccnt[row];
    __shared__ float sval[CCAP];
    __shared__ int   sidx[CCAP];
    const float* ei = emb + (size_t)row * DD;

    float4 a0 = reinterpret_cast<const float4*>(ei)[lane * 2];
    float4 a1 = reinterpret_cast<const float4*>(ei)[lane * 2 + 1];

    for (int base = wv * 2; base < cnt; base += 8) {
#pragma unroll
        for (int q = 0; q < 2; ++q) {
            int c = base + q;
            if (c >= cnt) break;
            const int j = cand[(size_t)row * CCAP + c];
            const float* ej = emb + (size_t)j * DD;
            float4 b0 = reinterpret_cast<const float4*>(ej)[lane * 2];
            float4 b1 = reinterpret_cast<const float4*>(ej)[lane * 2 + 1];
            float s = 0.f;
            s = fmaf(a0.x, b0.x, s); s = fmaf(a0.y, b0.y, s);
            s = fmaf(a0.z, b0.z, s); s = fmaf(a0.w, b0.w, s);
            s = fmaf(a1.x, b1.x, s); s = fmaf(a1.y, b1.y, s);
            s = fmaf(a1.z, b1.z, s); s = fmaf(a1.w, b1.w, s);
#pragma unroll
            for (int off = 32; off > 0; off >>= 1) s += __shfl_xor(s, off, 64);
            if (lane == 0) { sval[c] = s; sidx[c] = j; }
        }
    }
    __syncthreads();

    if (wv == 0) {
        float v[3]; int id[3];
#pragma unroll
        for (int k = 0; k < 3; ++k) {
            int s = lane + 64 * k;
            if (s < cnt) { v[k] = sval[s]; id[k] = sidx[s]; }
            else         { v[k] = -INFINITY; id[k] = 0x7fffffff; }
        }
#pragma unroll 1
        for (int sel = 0; sel < KTOP; ++sel) {
            float bv = v[0]; int bi = id[0];
#pragma unroll
            for (int k = 1; k < 3; ++k)
                if (v[k] > bv || (v[k] == bv && id[k] < bi)) { bv = v[k]; bi = id[k]; }
#pragma unroll
            for (int off = 1; off < 64; off <<= 1) {
                float ov = __shfl_xor(bv, off, 64);
                int   oi = __shfl_xor(bi, off, 64);
                if (ov > bv || (ov == bv && oi < bi)) { bv = ov; bi = oi; }
            }
            if (lane == 0) {
                tval[(size_t)row * KTOP + sel] = bv;
                tidx[(size_t)row * KTOP + sel] = bi;
            }
#pragma unroll
            for (int k = 0; k < 3; ++k)
                if (id[k] == bi) { v[k] = -INFINITY; id[k] = 0x7fffffff; }
        }
    }
}

// ---------------------------------------------------------------------------
// Scatter edges into dense adj + build per-row edge lists.
// ---------------------------------------------------------------------------
__global__ __launch_bounds__(256)
void scatter_kernel(const int* __restrict__ tidx, const float* __restrict__ tval,
                    float* __restrict__ adj, int* __restrict__ ecnt,
                    int* __restrict__ ej, float* __restrict__ ev) {
    int t = blockIdx.x * 256 + threadIdx.x;
    if (t >= NN * KTOP) return;
    int i = t / KTOP;
    int j = tidx[t];
    if (j == i || j < 0) return;
    float v = tval[t];
    if (v <= 0.f) return;
    v *= 0.5f;
    atomicAdd(adj + (size_t)i * NN + j, v);
    atomicAdd(adj + (size_t)j * NN + i, v);
    int pi = atomicAdd(ecnt + i, 1);
    if (pi < ECAP) { ej[(size_t)i * ECAP + pi] = j; ev[(size_t)i * ECAP + pi] = v; }
    int pj = atomicAdd(ecnt + j, 1);
    if (pj < ECAP) { ej[(size_t)j * ECAP + pj] = i; ev[(size_t)j * ECAP + pj] = v; }
}

// ---------------------------------------------------------------------------
// Sort each row's edge list by (j, valbits); compute sdeg. Dense fallback.
// ---------------------------------------------------------------------------
__global__ __launch_bounds__(256)
void sortdeg_kernel(int* __restrict__ ej, float* __restrict__ ev,
                    const int* __restrict__ ecnt, const float* __restrict__ adj,
                    float* __restrict__ sdeg) {
    const int row = blockIdx.x, tid = threadIdx.x;
    const int lane = tid & 63, wave = tid >> 6;
    const int nraw = ecnt[row];
    __shared__ float ws[4];

    if (nraw > ECAP) {
        const float4* rp = reinterpret_cast<const float4*>(adj + (size_t)row * NN);
        float sum = 0.f;
        for (int f = tid; f < NN / 4; f += 256) {
            float4 v = rp[f];
            sum += (v.x + v.y) + (v.z + v.w);
        }
#pragma unroll
        for (int off = 32; off > 0; off >>= 1) sum += __shfl_down(sum, off, 64);
        if (lane == 0) ws[wave] = sum;
        __syncthreads();
        if (tid == 0)
            sdeg[row] = 1.0f / (sqrtf(1.0f + ws[0] + ws[1] + ws[2] + ws[3]) + 1e-10f);
        return;
    }

    const int n = nraw;
    __shared__ int   lj[ECAP];
    __shared__ float lv[ECAP];
    __shared__ unsigned long long skey[ECAP];
    __shared__ int   oj[ECAP];
    __shared__ float ov[ECAP];
    if (tid < n) {
        int  jv = ej[(size_t)row * ECAP + tid];
        float vv = ev[(size_t)row * ECAP + tid];
        lj[tid] = jv; lv[tid] = vv;
        skey[tid] = ((unsigned long long)(unsigned)jv << 32) | (unsigned long long)ordkey(vv);
    }
    __syncthreads();
    if (tid < n) {
        unsigned long long mk = skey[tid];
        int rank = 0;
        for (int u = 0; u < n; ++u) {
            unsigned long long ku = skey[u];
            rank += (ku < mk || (ku == mk && u < tid)) ? 1 : 0;
        }
        oj[rank] = lj[tid];
        ov[rank] = lv[tid];
    }
    __syncthreads();
    if (tid < n) {
        ej[(size_t)row * ECAP + tid] = oj[tid];
        ev[(size_t)row * ECAP + tid] = ov[tid];
    }
    if (tid == 0) {
        float deg = 1.0f;
        for (int e = 0; e < n; ++e) deg += ov[e];
        sdeg[row] = 1.0f / (sqrtf(deg) + 1e-10f);
    }
}

// ---------------------------------------------------------------------------
// SpMM from sorted edge lists (deterministic); dense-scan fallback on ovf.
// ---------------------------------------------------------------------------
template<int COLS, bool DORELU>
__global__ __launch_bounds__(256)
void spmm_edges(const int* __restrict__ ej, const float* __restrict__ ev,
                const int* __restrict__ ecnt, const float* __restrict__ adj,
                const float* __restrict__ sdeg,
                const float* __restrict__ X, float* __restrict__ Y) {
    constexpr int CPT = COLS / 256;
    const int i = blockIdx.x;
    const int tid = threadIdx.x;
    const int lane = tid & 63, wave = tid >> 6;
    const float si = sdeg[i];
    const int nraw = ecnt[i];

    float acc[CPT];
#pragma unroll
    for (int c = 0; c < CPT; ++c) acc[c] = 0.f;

    if (nraw <= ECAP) {
        __shared__ int   s_j[ECAP];
        __shared__ float s_w[ECAP];
        if (tid < nraw) {
            int j = ej[(size_t)i * ECAP + tid];
            s_j[tid] = j;
            s_w[tid] = ev[(size_t)i * ECAP + tid] * sdeg[j];
        }
        __syncthreads();
#pragma unroll 4
        for (int e = 0; e < nraw; ++e) {
            int j = s_j[e];
            float we = s_w[e];
#pragma unroll
            for (int c = 0; c < CPT; ++c)
                acc[c] += we * X[(size_t)j * COLS + tid + c * 256];
        }
    } else {
        __shared__ int   s_j[256];
        __shared__ float s_w[256];
        __shared__ int   s_cnt[4];
        const float* rowp = adj + (size_t)i * NN;
        for (int j0 = 0; j0 < NN; j0 += 256) {
            float w = rowp[j0 + tid];
            bool nz = (w != 0.f);
            unsigned long long m = __ballot(nz);
            unsigned long long ltmask = (lane == 0) ? 0ull : (~0ull >> (64 - lane));
            int pre = __popcll(m & ltmask);
            if (lane == 0) s_cnt[wave] = __popcll(m);
            __syncthreads();
            int base = 0;
#pragma unroll
            for (int q = 0; q < 4; ++q)
                if (q < wave) base += s_cnt[q];
            int total = s_cnt[0] + s_cnt[1] + s_cnt[2] + s_cnt[3];
            if (nz) {
                int p = base + pre;
                s_j[p] = j0 + tid;
                s_w[p] = w * sdeg[j0 + tid];
            }
            __syncthreads();
            for (int e = 0; e < total; ++e) {
                int j = s_j[e];
                float we = s_w[e];
#pragma unroll
                for (int c = 0; c < CPT; ++c)
                    acc[c] += we * X[(size_t)j * COLS + tid + c * 256];
            }
            __syncthreads();
        }
    }

#pragma unroll
    for (int c = 0; c < CPT; ++c) {
        float val = si * (acc[c] + si * X[(size_t)i * COLS + tid + c * 256]);
        if (DORELU) val = fmaxf(val, 0.f);
        Y[(size_t)i * COLS + tid + c * 256] = val;
    }
}

// ---------------------------------------------------------------------------
extern "C" void kernel_launch(void* const* d_in, const int* in_sizes, int n_in,
                              void* d_out, int out_size, void* d_ws, size_t ws_size,
                              hipStream_t stream) {
    const float* features = (const float*)d_in[0];
    const float* masked   = (const float*)d_in[1];
    const float* W1  = (const float*)d_in[2];
    const float* b1  = (const float*)d_in[3];
    const float* W2  = (const float*)d_in[4];
    const float* b2  = (const float*)d_in[5];
    const float* Wg1 = (const float*)d_in[6];
    const float* bg1 = (const float*)d_in[7];
    const float* Wg2 = (const float*)d_in[8];
    const float* bg2 = (const float*)d_in[9];

    float* out_h3  = (float*)d_out;                      // [NN, DD]
    float* out_adj = (float*)d_out + (size_t)NN * DD;    // [NN, NN] (bf16 sim scratch too)
    unsigned short* simb = (unsigned short*)out_adj;     // bf16 sim view

    // ws layout:
    //  region A (NN*DD f32): h -> hi bf16 (first half) -> cand -> x2
    //  region B (NN*DD f32): emb -> x1/h1
    float* h    = (float*)d_ws;
    unsigned short* hi = (unsigned short*)h;              // NN*DD bf16 (8 MB)
    float* emb  = h + (size_t)NN * DD;
    float* tail = emb + (size_t)NN * DD;
    float* tval = tail;                                   // NN*KTOP
    int*   tidx = (int*)(tval + (size_t)NN * KTOP);       // NN*KTOP
    float* sdeg = (float*)(tidx + (size_t)NN * KTOP);     // NN
    int*   ecnt = (int*)(sdeg + NN);                      // NN
    int*   ccnt = ecnt + NN;                              // NN
    int*   elj  = ccnt + NN;                              // NN*ECAP
    float* elv  = (float*)(elj + (size_t)NN * ECAP);      // NN*ECAP
    int*   cand = (int*)h;                                // NN*CCAP (overlays hi, dead)
    float* x1 = emb;
    float* h1 = emb + (size_t)NN * HH;
    float* x2 = h;

    dim3 blk(256);

    sgemm128<false, 1><<<dim3((NN / 128) * (DD / 128)), blk, 0, stream>>>(
        features, W1, b1, h, NN, DD, DD);
    sgemm128<false, 0><<<dim3((NN / 128) * (DD / 128)), blk, 0, stream>>>(
        h, W2, b2, emb, NN, DD, DD);
    rownorm_kernel<<<dim3(NN), blk, 0, stream>>>(emb);
    cast_bf16_kernel<<<dim3(NN * DD / 1024), blk, 0, stream>>>(emb, hi);
    simgemm_bf16<<<dim3(4096), blk, 0, stream>>>(hi, simb);
    topk_cand_kernel<<<dim3(NN), blk, 0, stream>>>(simb, cand, ccnt);
    refine_kernel<<<dim3(NN), blk, 0, stream>>>(emb, cand, ccnt, tidx, tval);
    hipMemsetAsync(out_adj, 0, (size_t)NN * NN * sizeof(float), stream);
    hipMemsetAsync(ecnt, 0, (size_t)NN * sizeof(int), stream);
    scatter_kernel<<<dim3((NN * KTOP + 255) / 256), blk, 0, stream>>>(
        tidx, tval, out_adj, ecnt, elj, elv);
    sortdeg_kernel<<<dim3(NN), blk, 0, stream>>>(elj, elv, ecnt, out_adj, sdeg);
    sgemm128<false, 0><<<dim3((NN / 128) * (HH / 128)), blk, 0, stream>>>(
        masked, Wg1, bg1, x1, NN, HH, DD);
    spmm_edges<HH, true><<<dim3(NN), blk, 0, stream>>>(
        elj, elv, ecnt, out_adj, sdeg, x1, h1);
    sgemm128<false, 0><<<dim3((NN / 128) * (DD / 128)), blk, 0, stream>>>(
        h1, Wg2, bg2, x2, NN, DD, HH);
    spmm_edges<DD, false><<<dim3(NN), blk, 0, stream>>>(
        elj, elv, ecnt, out_adj, sdeg, x2, out_h3);
}

// Round 5
// 754.763 us; speedup vs baseline: 2.7278x; 1.0628x over previous
//
#include <hip/hip_runtime.h>
#include <cstdint>
#include <cstddef>

#define NN 8192
#define DD 512
#define HH 256
#define KTOP 21
#define CCAP 192   // candidate collection capacity
#define CMIN 48    // minimum candidates (superset of top-21 w/ bf16 margin)
#define ECAP 224   // per-row edge-list capacity
#define NBIN 1024

typedef __attribute__((ext_vector_type(8))) __bf16 bf16x8;
typedef __attribute__((ext_vector_type(4))) float f32x4;

__device__ __forceinline__ unsigned short f2bf(float x) {
    unsigned u = __float_as_uint(x);
    u += 0x7fffu + ((u >> 16) & 1u);
    return (unsigned short)(u >> 16);
}
__device__ __forceinline__ float bf2f(unsigned short h) {
    return __uint_as_float(((unsigned)h) << 16);
}
// order-preserving key: monotone map float -> uint (used by sortdeg)
__device__ __forceinline__ unsigned ordkey(float x) {
    unsigned b = __float_as_uint(x);
    return b ^ (((int)b >> 31) | 0x80000000u);
}

#define GLD16(gp, lp) __builtin_amdgcn_global_load_lds( \
    (const __attribute__((address_space(1))) unsigned int*)(gp), \
    (__attribute__((address_space(3))) unsigned int*)(lp), 16, 0, 0)

// ---------------------------------------------------------------------------
// fp32 SGEMM: kept for GEMM1/2 (emb path must stay fp32-exact for selection)
// ---------------------------------------------------------------------------
template<bool TRANSB, int ACT>
__global__ __launch_bounds__(256)
void sgemm128(const float* __restrict__ A, const float* __restrict__ B,
              const float* __restrict__ bias, float* __restrict__ C,
              int M, int N, int K) {
    constexpr int BM = 128, BN = 128, BK = 16;
    __shared__ float As[BK][BM + 4];
    __shared__ float Bs[BK][BN + 4];

    const int tiles_n = N / BN;
    const int by = blockIdx.x / tiles_n;
    const int bx = blockIdx.x % tiles_n;
    const int row0 = by * BM, col0 = bx * BN;
    const int tid = threadIdx.x;
    const int tx = tid & 15, ty = tid >> 4;

    float acc[8][8];
#pragma unroll
    for (int m = 0; m < 8; ++m)
#pragma unroll
        for (int n = 0; n < 8; ++n) acc[m][n] = 0.f;

    for (int k0 = 0; k0 < K; k0 += BK) {
#pragma unroll
        for (int l = 0; l < 2; ++l) {
            int f = tid + l * 256;
            int r = f >> 2, c4 = f & 3;
            float4 v = *reinterpret_cast<const float4*>(
                A + (size_t)(row0 + r) * K + k0 + c4 * 4);
            As[c4 * 4 + 0][r] = v.x;
            As[c4 * 4 + 1][r] = v.y;
            As[c4 * 4 + 2][r] = v.z;
            As[c4 * 4 + 3][r] = v.w;
        }
        if (TRANSB) {
#pragma unroll
            for (int l = 0; l < 2; ++l) {
                int f = tid + l * 256;
                int r = f >> 2, c4 = f & 3;
                float4 v = *reinterpret_cast<const float4*>(
                    B + (size_t)(col0 + r) * K + k0 + c4 * 4);
                Bs[c4 * 4 + 0][r] = v.x;
                Bs[c4 * 4 + 1][r] = v.y;
                Bs[c4 * 4 + 2][r] = v.z;
                Bs[c4 * 4 + 3][r] = v.w;
            }
        } else {
#pragma unroll
            for (int l = 0; l < 2; ++l) {
                int f = tid + l * 256;
                int kr = f >> 5, n4 = f & 31;
                *reinterpret_cast<float4*>(&Bs[kr][n4 * 4]) =
                    *reinterpret_cast<const float4*>(
                        B + (size_t)(k0 + kr) * N + col0 + n4 * 4);
            }
        }
        __syncthreads();

#pragma unroll
        for (int kk = 0; kk < BK; ++kk) {
            float a[8], b[8];
            *(float4*)&a[0] = *(const float4*)&As[kk][ty * 8];
            *(float4*)&a[4] = *(const float4*)&As[kk][ty * 8 + 4];
            *(float4*)&b[0] = *(const float4*)&Bs[kk][tx * 8];
            *(float4*)&b[4] = *(const float4*)&Bs[kk][tx * 8 + 4];
#pragma unroll
            for (int m = 0; m < 8; ++m)
#pragma unroll
                for (int n = 0; n < 8; ++n)
                    acc[m][n] = fmaf(a[m], b[n], acc[m][n]);
        }
        __syncthreads();
    }

    const int crow = row0 + ty * 8;
    const int ccol = col0 + tx * 8;
    float bv[8];
#pragma unroll
    for (int n = 0; n < 8; ++n) bv[n] = bias ? bias[ccol + n] : 0.f;
#pragma unroll
    for (int m = 0; m < 8; ++m) {
        float o[8];
#pragma unroll
        for (int n = 0; n < 8; ++n) {
            float t = acc[m][n] + bv[n];
            if (ACT == 1) t = fmaxf(t, 0.f);
            o[n] = t;
        }
        *reinterpret_cast<float4*>(C + (size_t)(crow + m) * N + ccol)     = *(float4*)&o[0];
        *reinterpret_cast<float4*>(C + (size_t)(crow + m) * N + ccol + 4) = *(float4*)&o[4];
    }
}

// ---------------------------------------------------------------------------
// Row L2-normalize + emit bf16 copy (fold the cast pass in)
// ---------------------------------------------------------------------------
__global__ __launch_bounds__(256)
void rownorm_emit_kernel(float* __restrict__ emb, unsigned short* __restrict__ ehi) {
    const int row = blockIdx.x, tid = threadIdx.x;
    float* rp = emb + (size_t)row * DD;
    float v0 = rp[tid], v1 = rp[tid + 256];
    float sum = v0 * v0 + v1 * v1;
#pragma unroll
    for (int off = 32; off > 0; off >>= 1) sum += __shfl_down(sum, off, 64);
    __shared__ float ws[4];
    __shared__ float sc_sh;
    if ((tid & 63) == 0) ws[tid >> 6] = sum;
    __syncthreads();
    if (tid == 0) {
        float n = sqrtf(ws[0] + ws[1] + ws[2] + ws[3]);
        sc_sh = 1.0f / fmaxf(n, 1e-12f);
    }
    __syncthreads();
    float sc = sc_sh;
    v0 *= sc; v1 *= sc;
    rp[tid] = v0;
    rp[tid + 256] = v1;
    ehi[(size_t)row * DD + tid]       = f2bf(v0);
    ehi[(size_t)row * DD + tid + 256] = f2bf(v1);
}

// ---------------------------------------------------------------------------
// Split fp32 -> (hi, lo) bf16 pair (for MFMA x1/x2 operands)
// ---------------------------------------------------------------------------
__global__ __launch_bounds__(256)
void split_kernel(const float* __restrict__ e, unsigned short* __restrict__ hi,
                  unsigned short* __restrict__ lo) {
    const int i = (blockIdx.x * 256 + threadIdx.x) * 4;
    float4 v = *reinterpret_cast<const float4*>(e + i);
    ushort4 h, l;
    h.x = f2bf(v.x); l.x = f2bf(v.x - bf2f(h.x));
    h.y = f2bf(v.y); l.y = f2bf(v.y - bf2f(h.y));
    h.z = f2bf(v.z); l.z = f2bf(v.z - bf2f(h.z));
    h.w = f2bf(v.w); l.w = f2bf(v.w - bf2f(h.w));
    *reinterpret_cast<ushort4*>(hi + i) = h;
    *reinterpret_cast<ushort4*>(lo + i) = l;
}

// ---------------------------------------------------------------------------
// Transpose + split weights: W [K,N] fp32 -> Thi/Tlo [N,K] bf16
// ---------------------------------------------------------------------------
__global__ __launch_bounds__(256)
void wtrans_kernel(const float* __restrict__ W, unsigned short* __restrict__ Thi,
                   unsigned short* __restrict__ Tlo, int K, int N) {
    int t = blockIdx.x * 256 + threadIdx.x;
    if (t >= K * N) return;
    int k = t / N, n = t - k * N;
    float x = W[t];
    unsigned short h = f2bf(x);
    Thi[(size_t)n * K + k] = h;
    Tlo[(size_t)n * K + k] = f2bf(x - bf2f(h));
}

// ---------------------------------------------------------------------------
// Zero the dense adjacency + ecnt (replaces hipMemsetAsync: exact 268 MB)
// ---------------------------------------------------------------------------
__global__ __launch_bounds__(256)
void zero_kernel(float4* __restrict__ adj4, float4* __restrict__ ecnt4) {
    const float4 z = {0.f, 0.f, 0.f, 0.f};
    size_t gid = (size_t)blockIdx.x * 256 + threadIdx.x;
    const size_t stride = (size_t)gridDim.x * 256;
    const size_t total = (size_t)NN * NN / 4;
    for (size_t i = gid; i < total; i += stride) adj4[i] = z;
    if (gid < NN / 4) ecnt4[gid] = z;
}

// ---------------------------------------------------------------------------
// approx sim = Ehi * Ehi^T (single bf16 MFMA product), output stored as bf16.
// ---------------------------------------------------------------------------
__global__ __launch_bounds__(256)
void simgemm_bf16(const unsigned short* __restrict__ Ehi,
                  unsigned short* __restrict__ Cb) {
    const int bid = blockIdx.x;
    const int swz = (bid & 7) * 512 + (bid >> 3);
    const int by = swz >> 6, bx = swz & 63;

    __shared__ unsigned short Ah[128 * 32];
    __shared__ unsigned short Bh[128 * 32];

    const int tid = threadIdx.x, lane = tid & 63, wid = tid >> 6;
    const int wm = wid >> 1, wn = wid & 1;
    const int fr = lane & 15, fq = lane >> 4;
    const int lrow = lane >> 2;
    const int lcol8 = (lane & 3) * 8;

    const size_t arow0 = (size_t)by * 128;
    const size_t brow0 = (size_t)bx * 128;

    f32x4 acc[4][4];
#pragma unroll
    for (int m = 0; m < 4; ++m)
#pragma unroll
        for (int n = 0; n < 4; ++n) acc[m][n] = (f32x4){0.f, 0.f, 0.f, 0.f};

    for (int k0 = 0; k0 < DD; k0 += 32) {
#pragma unroll
        for (int i = 0; i < 2; ++i) {
            const int chunk = wid + i * 4;
            const int grow = chunk * 16 + lrow;
            GLD16(Ehi + (arow0 + grow) * DD + (k0 + lcol8), Ah + chunk * 512);
            GLD16(Ehi + (brow0 + grow) * DD + (k0 + lcol8), Bh + chunk * 512);
        }
        __syncthreads();

        bf16x8 ah[4], bh[4];
#pragma unroll
        for (int mf = 0; mf < 4; ++mf)
            ah[mf] = *(const bf16x8*)&Ah[(wm * 64 + mf * 16 + fr) * 32 + fq * 8];
#pragma unroll
        for (int nf = 0; nf < 4; ++nf)
            bh[nf] = *(const bf16x8*)&Bh[(wn * 64 + nf * 16 + fr) * 32 + fq * 8];
#pragma unroll
        for (int mf = 0; mf < 4; ++mf)
#pragma unroll
            for (int nf = 0; nf < 4; ++nf)
                acc[mf][nf] = __builtin_amdgcn_mfma_f32_16x16x32_bf16(ah[mf], bh[nf], acc[mf][nf], 0, 0, 0);
        __syncthreads();
    }

#pragma unroll
    for (int mf = 0; mf < 4; ++mf) {
#pragma unroll
        for (int nf = 0; nf < 4; ++nf) {
            const size_t row = arow0 + wm * 64 + mf * 16 + fq * 4;
            const int col = bx * 128 + wn * 64 + nf * 16 + fr;
#pragma unroll
            for (int r2 = 0; r2 < 4; ++r2)
                Cb[(row + r2) * NN + col] = f2bf(acc[mf][nf][r2]);
        }
    }
}

// ---------------------------------------------------------------------------
// bf16x3 MFMA GEMM (NT): C[M,N] = Ahi/lo [M,K] @ (Bhi/lo [N,K])^T + bias
// For x1 = masked@Wg1+bg1 and x2 = h1@Wg2+bg2 (weights pre-transposed).
// ---------------------------------------------------------------------------
template<int KDIM>
__global__ __launch_bounds__(256)
void mfma_nt_bias(const unsigned short* __restrict__ Ahi,
                  const unsigned short* __restrict__ Alo,
                  const unsigned short* __restrict__ Bhi,
                  const unsigned short* __restrict__ Blo,
                  const float* __restrict__ bias, float* __restrict__ C, int N) {
    const int tiles_n = N / 128;
    const int by = blockIdx.x / tiles_n, bx = blockIdx.x % tiles_n;

    __shared__ unsigned short Ah[128 * 32];
    __shared__ unsigned short Al[128 * 32];
    __shared__ unsigned short Bh[128 * 32];
    __shared__ unsigned short Bl[128 * 32];

    const int tid = threadIdx.x, lane = tid & 63, wid = tid >> 6;
    const int wm = wid >> 1, wn = wid & 1;
    const int fr = lane & 15, fq = lane >> 4;
    const int lrow = lane >> 2;
    const int lcol8 = (lane & 3) * 8;

    const size_t arow0 = (size_t)by * 128;
    const size_t brow0 = (size_t)bx * 128;

    f32x4 acc[4][4];
#pragma unroll
    for (int m = 0; m < 4; ++m)
#pragma unroll
        for (int n = 0; n < 4; ++n) acc[m][n] = (f32x4){0.f, 0.f, 0.f, 0.f};

    for (int k0 = 0; k0 < KDIM; k0 += 32) {
#pragma unroll
        for (int i = 0; i < 2; ++i) {
            const int chunk = wid + i * 4;
            const int grow = chunk * 16 + lrow;
            GLD16(Ahi + (arow0 + grow) * KDIM + (k0 + lcol8), Ah + chunk * 512);
            GLD16(Alo + (arow0 + grow) * KDIM + (k0 + lcol8), Al + chunk * 512);
            GLD16(Bhi + (brow0 + grow) * KDIM + (k0 + lcol8), Bh + chunk * 512);
            GLD16(Blo + (brow0 + grow) * KDIM + (k0 + lcol8), Bl + chunk * 512);
        }
        __syncthreads();

        bf16x8 ah[4], al[4], bh[4], bl[4];
#pragma unroll
        for (int mf = 0; mf < 4; ++mf) {
            const int r = wm * 64 + mf * 16 + fr;
            ah[mf] = *(const bf16x8*)&Ah[r * 32 + fq * 8];
            al[mf] = *(const bf16x8*)&Al[r * 32 + fq * 8];
        }
#pragma unroll
        for (int nf = 0; nf < 4; ++nf) {
            const int r = wn * 64 + nf * 16 + fr;
            bh[nf] = *(const bf16x8*)&Bh[r * 32 + fq * 8];
            bl[nf] = *(const bf16x8*)&Bl[r * 32 + fq * 8];
        }
#pragma unroll
        for (int mf = 0; mf < 4; ++mf)
#pragma unroll
            for (int nf = 0; nf < 4; ++nf) {
                acc[mf][nf] = __builtin_amdgcn_mfma_f32_16x16x32_bf16(ah[mf], bh[nf], acc[mf][nf], 0, 0, 0);
                acc[mf][nf] = __builtin_amdgcn_mfma_f32_16x16x32_bf16(ah[mf], bl[nf], acc[mf][nf], 0, 0, 0);
                acc[mf][nf] = __builtin_amdgcn_mfma_f32_16x16x32_bf16(al[mf], bh[nf], acc[mf][nf], 0, 0, 0);
            }
        __syncthreads();
    }

#pragma unroll
    for (int mf = 0; mf < 4; ++mf) {
#pragma unroll
        for (int nf = 0; nf < 4; ++nf) {
            const size_t row = arow0 + wm * 64 + mf * 16 + fq * 4;
            const int col = bx * 128 + wn * 64 + nf * 16 + fr;
            const float bv = bias[col];
#pragma unroll
            for (int r2 = 0; r2 < 4; ++r2)
                C[(row + r2) * N + col] = acc[mf][nf][r2] + bv;
        }
    }
}

// ---------------------------------------------------------------------------
// One-pass histogram top-candidate selection on bf16 sim.
// ---------------------------------------------------------------------------
__global__ __launch_bounds__(256)
void topk_cand_kernel(const unsigned short* __restrict__ simb,
                      int* __restrict__ cand, int* __restrict__ ccnt) {
    const int row = blockIdx.x;
    const int tid = threadIdx.x;
    const int lane = tid & 63, wave = tid >> 6;
    const uint4* rp = reinterpret_cast<const uint4*>(simb + (size_t)row * NN);

    uint4 q[4];
#pragma unroll
    for (int t = 0; t < 4; ++t) q[t] = rp[t * 256 + tid];
    unsigned pk[16];
#pragma unroll
    for (int t = 0; t < 4; ++t) {
        pk[t * 4 + 0] = q[t].x; pk[t * 4 + 1] = q[t].y;
        pk[t * 4 + 2] = q[t].z; pk[t * 4 + 3] = q[t].w;
    }

    __shared__ int hist[NBIN];
    for (int b = tid; b < NBIN; b += 256) hist[b] = 0;
    __syncthreads();

    short bins[32];
#pragma unroll
    for (int u = 0; u < 16; ++u) {
        float flo = __uint_as_float(pk[u] << 16);
        float fhi = __uint_as_float(pk[u] & 0xFFFF0000u);
        int blo = (int)(flo * (float)NBIN); blo = max(0, min(NBIN - 1, blo));
        int bhi = (int)(fhi * (float)NBIN); bhi = max(0, min(NBIN - 1, bhi));
        bins[u * 2]     = (short)blo;
        bins[u * 2 + 1] = (short)bhi;
        atomicAdd(&hist[blo], 1);
        atomicAdd(&hist[bhi], 1);
    }
    __syncthreads();

    __shared__ int s_bstar;
    if (wave == 0) {
        int cum = 0, found = -1;
        for (int c0 = NBIN - 1; c0 >= 0 && found < 0; c0 -= 64) {
            int b = c0 - lane;
            int cnt = (b >= 0) ? hist[b] : 0;
            int sc = cnt;
#pragma unroll
            for (int off = 1; off < 64; off <<= 1) {
                int o = __shfl_up(sc, off, 64);
                if (lane >= off) sc += o;
            }
            int chunk_total = __shfl(sc, 63, 64);
            bool hit = (cum + sc >= CMIN);
            unsigned long long mh = __ballot(hit);
            if (mh) found = c0 - (__ffsll((long long)mh) - 1);
            else cum += chunk_total;
        }
        if (found < 0) found = 0;
        if (lane == 0) s_bstar = found;
    }
    __syncthreads();
    const int bstar = s_bstar;

    int cnt = 0;
#pragma unroll
    for (int i = 0; i < 32; ++i) cnt += (bins[i] >= bstar) ? 1 : 0;
    int sc = cnt;
#pragma unroll
    for (int off = 1; off < 64; off <<= 1) {
        int o = __shfl_up(sc, off, 64);
        if (lane >= off) sc += o;
    }
    __shared__ int wtot[4];
    if (lane == 63) wtot[wave] = sc;
    __syncthreads();
    int base = sc - cnt;
#pragma unroll
    for (int w = 0; w < 4; ++w)
        if (w < wave) base += wtot[w];
    int total = wtot[0] + wtot[1] + wtot[2] + wtot[3];

    int pos = base;
#pragma unroll
    for (int u = 0; u < 16; ++u) {
#pragma unroll
        for (int h = 0; h < 2; ++h) {
            if (bins[u * 2 + h] >= bstar) {
                if (pos < CCAP) {
                    int col = ((u >> 2) * 256 + tid) * 8 + (u & 3) * 2 + h;
                    cand[(size_t)row * CCAP + pos] = col;
                }
                pos++;
            }
        }
    }
    if (tid == 0) ccnt[row] = min(total, CCAP);
}

// ---------------------------------------------------------------------------
// Exact fp32 refine of candidates, final top-21 by (value desc, idx asc).
// ---------------------------------------------------------------------------
__global__ __launch_bounds__(256)
void refine_kernel(const float* __restrict__ emb, const int* __restrict__ cand,
                   const int* __restrict__ ccnt,
                   int* __restrict__ tidx, float* __restrict__ tval) {
    const int row = blockIdx.x;
    const int tid = threadIdx.x, lane = tid & 63, wv = tid >> 6;
    const int cnt = ccnt[row];
    __shared__ float sval[CCAP];
    __shared__ int   sidx[CCAP];
    const float* ei = emb + (size_t)row * DD;

    float4 a0 = reinterpret_cast<const float4*>(ei)[lane * 2];
    float4 a1 = reinterpret_cast<const float4*>(ei)[lane * 2 + 1];

    for (int base = wv * 2; base < cnt; base += 8) {
#pragma unroll
        for (int q = 0; q < 2; ++q) {
            int c = base + q;
            if (c >= cnt) break;
            const int j = cand[(size_t)row * CCAP + c];
            const float* ej = emb + (size_t)j * DD;
            float4 b0 = reinterpret_cast<const float4*>(ej)[lane * 2];
            float4 b1 = reinterpret_cast<const float4*>(ej)[lane * 2 + 1];
            float s = 0.f;
            s = fmaf(a0.x, b0.x, s); s = fmaf(a0.y, b0.y, s);
            s = fmaf(a0.z, b0.z, s); s = fmaf(a0.w, b0.w, s);
            s = fmaf(a1.x, b1.x, s); s = fmaf(a1.y, b1.y, s);
            s = fmaf(a1.z, b1.z, s); s = fmaf(a1.w, b1.w, s);
#pragma unroll
            for (int off = 32; off > 0; off >>= 1) s += __shfl_xor(s, off, 64);
            if (lane == 0) { sval[c] = s; sidx[c] = j; }
        }
    }
    __syncthreads();

    if (wv == 0) {
        float v[3]; int id[3];
#pragma unroll
        for (int k = 0; k < 3; ++k) {
            int s = lane + 64 * k;
            if (s < cnt) { v[k] = sval[s]; id[k] = sidx[s]; }
            else         { v[k] = -INFINITY; id[k] = 0x7fffffff; }
        }
#pragma unroll 1
        for (int sel = 0; sel < KTOP; ++sel) {
            float bv = v[0]; int bi = id[0];
#pragma unroll
            for (int k = 1; k < 3; ++k)
                if (v[k] > bv || (v[k] == bv && id[k] < bi)) { bv = v[k]; bi = id[k]; }
#pragma unroll
            for (int off = 1; off < 64; off <<= 1) {
                float ov = __shfl_xor(bv, off, 64);
                int   oi = __shfl_xor(bi, off, 64);
                if (ov > bv || (ov == bv && oi < bi)) { bv = ov; bi = oi; }
            }
            if (lane == 0) {
                tval[(size_t)row * KTOP + sel] = bv;
                tidx[(size_t)row * KTOP + sel] = bi;
            }
#pragma unroll
            for (int k = 0; k < 3; ++k)
                if (id[k] == bi) { v[k] = -INFINITY; id[k] = 0x7fffffff; }
        }
    }
}

// ---------------------------------------------------------------------------
// Scatter edges into dense adj + build per-row edge lists.
// ---------------------------------------------------------------------------
__global__ __launch_bounds__(256)
void scatter_kernel(const int* __restrict__ tidx, const float* __restrict__ tval,
                    float* __restrict__ adj, int* __restrict__ ecnt,
                    int* __restrict__ ej, float* __restrict__ ev) {
    int t = blockIdx.x * 256 + threadIdx.x;
    if (t >= NN * KTOP) return;
    int i = t / KTOP;
    int j = tidx[t];
    if (j == i || j < 0) return;
    float v = tval[t];
    if (v <= 0.f) return;
    v *= 0.5f;
    atomicAdd(adj + (size_t)i * NN + j, v);
    atomicAdd(adj + (size_t)j * NN + i, v);
    int pi = atomicAdd(ecnt + i, 1);
    if (pi < ECAP) { ej[(size_t)i * ECAP + pi] = j; ev[(size_t)i * ECAP + pi] = v; }
    int pj = atomicAdd(ecnt + j, 1);
    if (pj < ECAP) { ej[(size_t)j * ECAP + pj] = i; ev[(size_t)j * ECAP + pj] = v; }
}

// ---------------------------------------------------------------------------
// Sort each row's edge list by (j, valbits); compute sdeg. Dense fallback.
// ---------------------------------------------------------------------------
__global__ __launch_bounds__(256)
void sortdeg_kernel(int* __restrict__ ej, float* __restrict__ ev,
                    const int* __restrict__ ecnt, const float* __restrict__ adj,
                    float* __restrict__ sdeg) {
    const int row = blockIdx.x, tid = threadIdx.x;
    const int lane = tid & 63, wave = tid >> 6;
    const int nraw = ecnt[row];
    __shared__ float ws[4];

    if (nraw > ECAP) {
        const float4* rp = reinterpret_cast<const float4*>(adj + (size_t)row * NN);
        float sum = 0.f;
        for (int f = tid; f < NN / 4; f += 256) {
            float4 v = rp[f];
            sum += (v.x + v.y) + (v.z + v.w);
        }
#pragma unroll
        for (int off = 32; off > 0; off >>= 1) sum += __shfl_down(sum, off, 64);
        if (lane == 0) ws[wave] = sum;
        __syncthreads();
        if (tid == 0)
            sdeg[row] = 1.0f / (sqrtf(1.0f + ws[0] + ws[1] + ws[2] + ws[3]) + 1e-10f);
        return;
    }

    const int n = nraw;
    __shared__ int   lj[ECAP];
    __shared__ float lv[ECAP];
    __shared__ unsigned long long skey[ECAP];
    __shared__ int   oj[ECAP];
    __shared__ float ov[ECAP];
    if (tid < n) {
        int  jv = ej[(size_t)row * ECAP + tid];
        float vv = ev[(size_t)row * ECAP + tid];
        lj[tid] = jv; lv[tid] = vv;
        skey[tid] = ((unsigned long long)(unsigned)jv << 32) | (unsigned long long)ordkey(vv);
    }
    __syncthreads();
    if (tid < n) {
        unsigned long long mk = skey[tid];
        int rank = 0;
        for (int u = 0; u < n; ++u) {
            unsigned long long ku = skey[u];
            rank += (ku < mk || (ku == mk && u < tid)) ? 1 : 0;
        }
        oj[rank] = lj[tid];
        ov[rank] = lv[tid];
    }
    __syncthreads();
    if (tid < n) {
        ej[(size_t)row * ECAP + tid] = oj[tid];
        ev[(size_t)row * ECAP + tid] = ov[tid];
    }
    if (tid == 0) {
        float deg = 1.0f;
        for (int e = 0; e < n; ++e) deg += ov[e];
        sdeg[row] = 1.0f / (sqrtf(deg) + 1e-10f);
    }
}

// ---------------------------------------------------------------------------
// SpMM from sorted edge lists (deterministic); dense-scan fallback on ovf.
// ---------------------------------------------------------------------------
template<int COLS, bool DORELU>
__global__ __launch_bounds__(256)
void spmm_edges(const int* __restrict__ ej, const float* __restrict__ ev,
                const int* __restrict__ ecnt, const float* __restrict__ adj,
                const float* __restrict__ sdeg,
                const float* __restrict__ X, float* __restrict__ Y) {
    constexpr int CPT = COLS / 256;
    const int i = blockIdx.x;
    const int tid = threadIdx.x;
    const int lane = tid & 63, wave = tid >> 6;
    const float si = sdeg[i];
    const int nraw = ecnt[i];

    float acc[CPT];
#pragma unroll
    for (int c = 0; c < CPT; ++c) acc[c] = 0.f;

    if (nraw <= ECAP) {
        __shared__ int   s_j[ECAP];
        __shared__ float s_w[ECAP];
        if (tid < nraw) {
            int j = ej[(size_t)i * ECAP + tid];
            s_j[tid] = j;
            s_w[tid] = ev[(size_t)i * ECAP + tid] * sdeg[j];
        }
        __syncthreads();
#pragma unroll 4
        for (int e = 0; e < nraw; ++e) {
            int j = s_j[e];
            float we = s_w[e];
#pragma unroll
            for (int c = 0; c < CPT; ++c)
                acc[c] += we * X[(size_t)j * COLS + tid + c * 256];
        }
    } else {
        __shared__ int   s_j[256];
        __shared__ float s_w[256];
        __shared__ int   s_cnt[4];
        const float* rowp = adj + (size_t)i * NN;
        for (int j0 = 0; j0 < NN; j0 += 256) {
            float w = rowp[j0 + tid];
            bool nz = (w != 0.f);
            unsigned long long m = __ballot(nz);
            unsigned long long ltmask = (lane == 0) ? 0ull : (~0ull >> (64 - lane));
            int pre = __popcll(m & ltmask);
            if (lane == 0) s_cnt[wave] = __popcll(m);
            __syncthreads();
            int base = 0;
#pragma unroll
            for (int q = 0; q < 4; ++q)
                if (q < wave) base += s_cnt[q];
            int total = s_cnt[0] + s_cnt[1] + s_cnt[2] + s_cnt[3];
            if (nz) {
                int p = base + pre;
                s_j[p] = j0 + tid;
                s_w[p] = w * sdeg[j0 + tid];
            }
            __syncthreads();
            for (int e = 0; e < total; ++e) {
                int j = s_j[e];
                float we = s_w[e];
#pragma unroll
                for (int c = 0; c < CPT; ++c)
                    acc[c] += we * X[(size_t)j * COLS + tid + c * 256];
            }
            __syncthreads();
        }
    }

#pragma unroll
    for (int c = 0; c < CPT; ++c) {
        float val = si * (acc[c] + si * X[(size_t)i * COLS + tid + c * 256]);
        if (DORELU) val = fmaxf(val, 0.f);
        Y[(size_t)i * COLS + tid + c * 256] = val;
    }
}

// ---------------------------------------------------------------------------
extern "C" void kernel_launch(void* const* d_in, const int* in_sizes, int n_in,
                              void* d_out, int out_size, void* d_ws, size_t ws_size,
                              hipStream_t stream) {
    const float* features = (const float*)d_in[0];
    const float* masked   = (const float*)d_in[1];
    const float* W1  = (const float*)d_in[2];
    const float* b1  = (const float*)d_in[3];
    const float* W2  = (const float*)d_in[4];
    const float* b2  = (const float*)d_in[5];
    const float* Wg1 = (const float*)d_in[6];
    const float* bg1 = (const float*)d_in[7];
    const float* Wg2 = (const float*)d_in[8];
    const float* bg2 = (const float*)d_in[9];

    float* out_h3  = (float*)d_out;                      // [NN, DD]
    float* out_adj = (float*)d_out + (size_t)NN * DD;    // [NN, NN] (bf16 sim scratch too)
    unsigned short* simb = (unsigned short*)out_adj;     // bf16 sim view

    // ws layout:
    //  region A (NN*DD f32 = 16.8MB):
    //    phase1: h (GEMM1 out / GEMM2 in)
    //    phase2: ehi bf16 [0..8.4MB) ; cand ints [8.4..14.7MB)
    //    phase3: mhi/mlo bf16 [0..8.4),[8.4..16.8)
    //    phase4: h1hi/h1lo bf16 [0..4.2),[4.2..8.4)
    //  region B (NN*DD f32): emb -> x1 [0..8.4) / h1 [8.4..16.8) -> x2 (full)
    //  tail: tval,tidx,sdeg,ecnt,ccnt,elj,elv,wt1hi/lo,wt2hi/lo
    float* Areg = (float*)d_ws;
    float* Breg = Areg + (size_t)NN * DD;
    float* tail = Breg + (size_t)NN * DD;

    float* h    = Areg;
    unsigned short* ehi = (unsigned short*)Areg;          // NN*DD bf16 (8.4MB)
    int*   cand = (int*)(Areg + (size_t)NN * DD / 2);     // NN*CCAP ints
    unsigned short* mhi = (unsigned short*)Areg;          // NN*DD bf16
    unsigned short* mlo = mhi + (size_t)NN * DD;
    unsigned short* h1hi = (unsigned short*)Areg;         // NN*HH bf16
    unsigned short* h1lo = h1hi + (size_t)NN * HH;

    float* emb = Breg;
    float* x1  = Breg;                                    // [NN,HH] fp32
    float* h1  = Breg + (size_t)NN * HH;                  // [NN,HH] fp32
    float* x2  = Breg;                                    // [NN,DD] fp32

    float* tval = tail;                                   // NN*KTOP
    int*   tidx = (int*)(tval + (size_t)NN * KTOP);       // NN*KTOP
    float* sdeg = (float*)(tidx + (size_t)NN * KTOP);     // NN
    int*   ecnt = (int*)(sdeg + NN);                      // NN
    int*   ccnt = ecnt + NN;                              // NN
    int*   elj  = ccnt + NN;                              // NN*ECAP
    float* elv  = (float*)(elj + (size_t)NN * ECAP);      // NN*ECAP
    unsigned short* wt1hi = (unsigned short*)(elv + (size_t)NN * ECAP); // HH*DD
    unsigned short* wt1lo = wt1hi + (size_t)HH * DD;
    unsigned short* wt2hi = wt1lo + (size_t)HH * DD;      // DD*HH
    unsigned short* wt2lo = wt2hi + (size_t)DD * HH;

    dim3 blk(256);

    // 1-2) MLP (fp32 — selection accuracy depends on emb)
    sgemm128<false, 1><<<dim3((NN / 128) * (DD / 128)), blk, 0, stream>>>(
        features, W1, b1, h, NN, DD, DD);
    sgemm128<false, 0><<<dim3((NN / 128) * (DD / 128)), blk, 0, stream>>>(
        h, W2, b2, emb, NN, DD, DD);
    // 3) normalize + emit bf16 (h dead -> ehi overlays it)
    rownorm_emit_kernel<<<dim3(NN), blk, 0, stream>>>(emb, ehi);
    // 4) approx sim (bf16 in/out) -> out_adj scratch
    simgemm_bf16<<<dim3(4096), blk, 0, stream>>>(ehi, simb);
    // 5) histogram candidate selection
    topk_cand_kernel<<<dim3(NN), blk, 0, stream>>>(simb, cand, ccnt);
    // 6) exact fp32 refine + final top-21
    refine_kernel<<<dim3(NN), blk, 0, stream>>>(emb, cand, ccnt, tidx, tval);
    // 7) zero adjacency + ecnt (custom: exact 268 MB of float4 stores)
    zero_kernel<<<dim3(2048), blk, 0, stream>>>(
        (float4*)out_adj, (float4*)ecnt);
    // 8) scatter edges + build edge lists
    scatter_kernel<<<dim3((NN * KTOP + 255) / 256), blk, 0, stream>>>(
        tidx, tval, out_adj, ecnt, elj, elv);
    // 9) sort edge lists + degree
    sortdeg_kernel<<<dim3(NN), blk, 0, stream>>>(elj, elv, ecnt, out_adj, sdeg);
    // 10-12) x1 = masked @ Wg1 + bg1 via bf16x3 MFMA
    split_kernel<<<dim3(NN * DD / 1024), blk, 0, stream>>>(masked, mhi, mlo);
    wtrans_kernel<<<dim3(DD * HH / 256), blk, 0, stream>>>(Wg1, wt1hi, wt1lo, DD, HH);
    mfma_nt_bias<DD><<<dim3((NN / 128) * (HH / 128)), blk, 0, stream>>>(
        mhi, mlo, wt1hi, wt1lo, bg1, x1, HH);
    // 13) h1 = relu(Ahat @ x1)
    spmm_edges<HH, true><<<dim3(NN), blk, 0, stream>>>(
        elj, elv, ecnt, out_adj, sdeg, x1, h1);
    // 14-16) x2 = h1 @ Wg2 + bg2 via bf16x3 MFMA (h1 split overlays mhi)
    split_kernel<<<dim3(NN * HH / 1024), blk, 0, stream>>>(h1, h1hi, h1lo);
    wtrans_kernel<<<dim3(HH * DD / 256), blk, 0, stream>>>(Wg2, wt2hi, wt2lo, HH, DD);
    mfma_nt_bias<HH><<<dim3((NN / 128) * (DD / 128)), blk, 0, stream>>>(
        h1hi, h1lo, wt2hi, wt2lo, bg2, x2, DD);
    // 17) h3 = Ahat @ x2 -> d_out
    spmm_edges<DD, false><<<dim3(NN), blk, 0, stream>>>(
        elj, elv, ecnt, out_adj, sdeg, x2, out_h3);
}